// Round 5
// baseline (6425.300 us; speedup 1.0000x reference)
//
#include <hip/hip_runtime.h>
#include <cstdint>
#include <cstddef>

#define DEVI __device__ __forceinline__

static constexpr int HW = 65536;          // 256*256
static constexpr float PTOTF = 524288.0f; // 8*256*256

typedef __attribute__((ext_vector_type(8))) short bfx8;
typedef __attribute__((ext_vector_type(16))) float fx16;

DEVI unsigned short f2bf(float f) {
  unsigned int x = __float_as_uint(f);
  x += 0x7fffu + ((x >> 16) & 1u);
  return (unsigned short)(x >> 16);
}
DEVI float celuf(float v) { return v > 0.0f ? v : expm1f(v); }

DEVI void unpack8(const uint4 u, float* v) {
  v[0] = __uint_as_float(u.x << 16); v[1] = __uint_as_float(u.x & 0xffff0000u);
  v[2] = __uint_as_float(u.y << 16); v[3] = __uint_as_float(u.y & 0xffff0000u);
  v[4] = __uint_as_float(u.z << 16); v[5] = __uint_as_float(u.z & 0xffff0000u);
  v[6] = __uint_as_float(u.w << 16); v[7] = __uint_as_float(u.w & 0xffff0000u);
}

// padded pixel base index: interior (n,h,w) -> element offset/64
DEVI size_t padpx(int n, int h, int w) {
  return ((size_t)n * 258 + (h + 1)) * 258 + (w + 1);
}

// ---- weight transform: src [OC][IC][3][3] -> dst [9][ICP][OCP] fp32 (conv1/last)
__global__ void k_wt(const float* __restrict__ w, float* __restrict__ dst,
                     int OC, int IC, int ICP, int OCP) {
  const int tot = 9 * ICP * OCP;
  for (int idx = blockIdx.x * blockDim.x + threadIdx.x; idx < tot;
       idx += gridDim.x * blockDim.x) {
    const int tap = idx / (ICP * OCP);
    const int r = idx - tap * (ICP * OCP);
    const int ic = r / OCP, oc = r - ic * OCP;
    dst[idx] = (ic < IC && oc < OC) ? w[(oc * IC + ic) * 9 + tap] : 0.0f;
  }
}

// ---- main-weight transform: bw [6][64][64][3][3] fp32 -> [6][9][64][64] bf16,
// ic-chunk XOR-swizzled so linear LDS staging yields conflict-free frag reads.
__global__ void k_wtm(const float* __restrict__ w, unsigned short* __restrict__ dst) {
  const int idx = blockIdx.x * 256 + threadIdx.x;
  if (idx >= 6 * 36864) return;
  const int cv = idx / 36864, r = idx - cv * 36864;
  const int tap = r >> 12, rr = r & 4095, oc = rr >> 6, ic = rr & 63;
  const float v = w[((size_t)cv * 4096 + oc * 64 + ic) * 9 + tap];
  const int dic = ((((ic >> 3) ^ (oc & 7)) << 3) | (ic & 7));
  dst[(size_t)cv * 36864 + tap * 4096 + oc * 64 + dic] = f2bf(v);
}

// ---- zero the 1-px pad border of the three padded NHWC buffers
__global__ void k_padzero(unsigned short* a, unsigned short* b, unsigned short* c) {
  const int id = blockIdx.x * 256 + threadIdx.x;
  if (id >= 3 * 8 * 1028) return;
  const int buf = id / (8 * 1028), r = id - buf * (8 * 1028);
  const int n = r / 1028, k = r - n * 1028;
  int hp, wp;
  if (k < 258)      { hp = 0;           wp = k; }
  else if (k < 516) { hp = 257;         wp = k - 258; }
  else if (k < 772) { hp = k - 516 + 1; wp = 0; }
  else              { hp = k - 772 + 1; wp = 257; }
  unsigned short* p = (buf == 0 ? a : buf == 1 ? b : c) +
                      (((size_t)n * 258 + hp) * 258 + wp) * 64;
  const uint4 z = {0, 0, 0, 0};
#pragma unroll
  for (int q = 0; q < 8; ++q) ((uint4*)p)[q] = z;
}

// ---- instance norm stats: one block per (n,c)
__global__ __launch_bounds__(256)
void k_inorm(const float* __restrict__ x, float* __restrict__ ms) {
  __shared__ float s1[256], s2[256];
  const int b = blockIdx.x;
  const float4* p = (const float4*)(x + (size_t)b * HW);
  float sum = 0.f, sq = 0.f;
  for (int j = threadIdx.x; j < HW / 4; j += 256) {
    const float4 v = p[j];
    sum += v.x + v.y + v.z + v.w;
    sq  += v.x * v.x + v.y * v.y + v.z * v.z + v.w * v.w;
  }
  s1[threadIdx.x] = sum; s2[threadIdx.x] = sq;
  __syncthreads();
  for (int s = 128; s > 0; s >>= 1) {
    if ((int)threadIdx.x < s) {
      s1[threadIdx.x] += s1[threadIdx.x + s];
      s2[threadIdx.x] += s2[threadIdx.x + s];
    }
    __syncthreads();
  }
  if (threadIdx.x == 0) {
    const float m = s1[0] * (1.0f / HW);
    const float var = (s2[0] - s1[0] * s1[0] * (1.0f / HW)) * (1.0f / (HW - 1));
    ms[2 * b] = m;
    ms[2 * b + 1] = rsqrtf(var);
  }
}

// ---- conv1 (6->64), VALU path, writes PADDED raw bf16 output
__global__ __launch_bounds__(256)
void k_conv1(const float* __restrict__ x, const float* __restrict__ ms,
             const float* __restrict__ wt, unsigned short* __restrict__ out) {
  __shared__ float in_s[3 * 66 * 9];
  __shared__ float w_s[9 * 8 * 64];

  const int t = threadIdx.x;
  const int b = blockIdx.x;
  const int n = b >> 10;
  const int h = (b >> 2) & 255;
  const int w0 = (b & 3) << 6;

  const float m0 = ms[6 * n + 0], r0 = ms[6 * n + 1];
  const float m1 = ms[6 * n + 2], r1 = ms[6 * n + 3];
  const float m2 = ms[6 * n + 4], r2 = ms[6 * n + 5];

  const int oc0 = (t & 15) * 4;
  const int px0 = (t >> 4) * 4;
  float acc[4][4] = {{0.f}};

  {  // stage weights [9][8][64]
    const float4* wsrc = (const float4*)wt;
    for (int j4 = t; j4 < 1152; j4 += 256) ((float4*)w_s)[j4] = wsrc[j4];
  }
  if (t < 198) {  // stage input tile
    const int dh = t / 66, px = t - dh * 66;
    const int gh = h + dh - 1, gw = w0 + px - 1;
    const bool ok = ((unsigned)gh < 256u) && ((unsigned)gw < 256u);
    float v[8];
    if (ok) {
      const float* xp = x + (size_t)n * 3 * HW + gh * 256 + gw;
      const float a0 = xp[0], a1 = xp[HW], a2 = xp[2 * HW];
      v[0] = a0; v[1] = a1; v[2] = a2;
      v[3] = (a0 - m0) * r0; v[4] = (a1 - m1) * r1; v[5] = (a2 - m2) * r2;
      v[6] = 0.f; v[7] = 0.f;
    } else {
#pragma unroll
      for (int q = 0; q < 8; ++q) v[q] = 0.f;
    }
    float* d = &in_s[(dh * 66 + px) * 9];
#pragma unroll
    for (int q = 0; q < 8; ++q) d[q] = v[q];
  }
  __syncthreads();
#pragma unroll
  for (int i = 0; i < 8; ++i) {
    float xv[3][6];
#pragma unroll
    for (int dh = 0; dh < 3; ++dh)
#pragma unroll
      for (int j = 0; j < 6; ++j)
        xv[dh][j] = in_s[(dh * 66 + px0 + j) * 9 + i];
#pragma unroll
    for (int dh = 0; dh < 3; ++dh)
#pragma unroll
      for (int dw = 0; dw < 3; ++dw) {
        const float4 wv = *(const float4*)&w_s[((dh * 3 + dw) * 8 + i) * 64 + oc0];
#pragma unroll
        for (int p = 0; p < 4; ++p) {
          const float xin = xv[dh][p + dw];
          acc[p][0] += xin * wv.x;
          acc[p][1] += xin * wv.y;
          acc[p][2] += xin * wv.z;
          acc[p][3] += xin * wv.w;
        }
      }
  }
  unsigned short* ob = out + (((size_t)n * 258 + (h + 1)) * 258 + (w0 + 1)) * 64;
#pragma unroll
  for (int p = 0; p < 4; ++p) {
    ushort4 o;
    o.x = f2bf(acc[p][0]); o.y = f2bf(acc[p][1]);
    o.z = f2bf(acc[p][2]); o.w = f2bf(acc[p][3]);
    *(ushort4*)(ob + (size_t)(px0 + p) * 64 + oc0) = o;
  }
}

// ---- MFMA implicit-GEMM 3x3 conv 64->64, padded bf16 NHWC in/out.
// MODE 1: input is activation (identity). MODE 2: input is raw; apply
// BN (scale/shift) + CELU at staging (pad positions forced to zero).
// Block: 4 rows x 64 px x 64 oc; wave wv owns row wv. D[oc][px] orientation.
// Fused BN partial stats -> psum/psq[block][64].
template<int MODE>
__global__ __launch_bounds__(256, 2)
void k_mconv(const unsigned short* __restrict__ in, const float* __restrict__ bnp,
             const unsigned short* __restrict__ wsw, unsigned short* __restrict__ out,
             float* __restrict__ psum, float* __restrict__ psq) {
  __shared__ __align__(16) unsigned short a_s[6 * 66 * 64];
  __shared__ __align__(16) unsigned short w_s[2][4096];
  __shared__ float s_red[2][4][64];
  __shared__ float s_sc[64], s_sh[64];

  const int t = threadIdx.x;
  const int lane = t & 63, wv = t >> 6;
  int b = blockIdx.x;
  b = (b & 7) * 256 + (b >> 3);  // XCD swizzle (2048 = 8*256, bijective)
  const int n  = b >> 8;
  const int h0 = ((b >> 2) & 63) * 4;
  const int w0 = (b & 3) * 64;

  if (MODE == 2) {
    if (t < 64) { s_sc[t] = bnp[t]; s_sh[t] = bnp[64 + t]; }
    __syncthreads();
  }

  // issue tap-0 weight loads (global layout pre-swizzled -> linear copy)
  const uint4* wsrc0 = (const uint4*)wsw;
  const uint4 wz0 = wsrc0[t], wz1 = wsrc0[t + 256];

  // ---- stage A tile [6 rows][66 px][64 ic], XOR-swizzled (3168 x 16B chunks)
  const size_t ibase = ((size_t)n * 258 + h0) * 258 + w0;
  for (int j = t; j < 3168; j += 256) {
    const int r  = j / 528;           // 528 = 66 px * 8 chunks
    const int c  = j - r * 528;
    const int px = c >> 3, sl = c & 7;
    uint4 u = *(const uint4*)(in + (ibase + (size_t)r * 258 + px) * 64 + sl * 8);
    if (MODE == 2) {
      const int hp = h0 + r, wp = w0 + px;
      const bool pad = (hp == 0) | (hp == 257) | (wp == 0) | (wp == 257);
      float vv[8];
      unpack8(u, vv);
#pragma unroll
      for (int q = 0; q < 8; ++q) {
        const float z = vv[q] * s_sc[sl * 8 + q] + s_sh[sl * 8 + q];
        vv[q] = pad ? 0.f : celuf(z);
      }
      uint4 o;
      o.x = (unsigned)f2bf(vv[0]) | ((unsigned)f2bf(vv[1]) << 16);
      o.y = (unsigned)f2bf(vv[2]) | ((unsigned)f2bf(vv[3]) << 16);
      o.z = (unsigned)f2bf(vv[4]) | ((unsigned)f2bf(vv[5]) << 16);
      o.w = (unsigned)f2bf(vv[6]) | ((unsigned)f2bf(vv[7]) << 16);
      u = o;
    }
    const int R = r * 66 + px;
    *(uint4*)((char*)a_s + (size_t)R * 128 + ((sl ^ (R & 7)) << 4)) = u;
  }
  ((uint4*)w_s[0])[t] = wz0;
  ((uint4*)w_s[0])[t + 256] = wz1;
  __syncthreads();

  fx16 acc[2][2] = {};

#pragma unroll
  for (int tap = 0; tap < 9; ++tap) {
    const int dh = tap / 3, dw = tap - dh * 3;
    uint4 wn0, wn1;
    if (tap < 8) {  // issue next-tap weight loads (written after compute)
      const uint4* wsrc = (const uint4*)(wsw + (size_t)(tap + 1) * 4096);
      wn0 = wsrc[t]; wn1 = wsrc[t + 256];
    }
    const unsigned short* wbuf = w_s[tap & 1];
    bfx8 af[2][4];
#pragma unroll
    for (int m = 0; m < 2; ++m)
#pragma unroll
      for (int ks = 0; ks < 4; ++ks) {
        const int oc = m * 32 + (lane & 31);
        const int sl = (ks * 2 + (lane >> 5)) ^ (oc & 7);
        af[m][ks] = *(const bfx8*)((const char*)wbuf + oc * 128 + (sl << 4));
      }
#pragma unroll
    for (int ks = 0; ks < 4; ++ks) {
      bfx8 bf[2];
#pragma unroll
      for (int nn = 0; nn < 2; ++nn) {
        const int px = nn * 32 + (lane & 31) + dw;
        const int R = (wv + dh) * 66 + px;
        const int sl = (ks * 2 + (lane >> 5)) ^ (R & 7);
        bf[nn] = *(const bfx8*)((const char*)a_s + (size_t)R * 128 + (sl << 4));
      }
#pragma unroll
      for (int m = 0; m < 2; ++m)
#pragma unroll
        for (int nn = 0; nn < 2; ++nn)
          acc[m][nn] = __builtin_amdgcn_mfma_f32_32x32x16_bf16(
              af[m][ks], bf[nn], acc[m][nn], 0, 0, 0);
    }
    if (tap < 8) {
      uint4* wdst = (uint4*)w_s[(tap + 1) & 1];
      wdst[t] = wn0; wdst[t + 256] = wn1;
    }
    __syncthreads();
  }

  // ---- store C: D rows = oc (4 contiguous per reg-quad), cols = px
  const size_t obase = (((size_t)n * 258 + (h0 + wv + 1)) * 258 + (w0 + 1)) * 64;
#pragma unroll
  for (int m = 0; m < 2; ++m)
#pragma unroll
    for (int nn = 0; nn < 2; ++nn) {
      const int px = nn * 32 + (lane & 31);
#pragma unroll
      for (int q = 0; q < 4; ++q) {
        const int ocb = m * 32 + q * 8 + 4 * (lane >> 5);
        ushort4 o;
        o.x = f2bf(acc[m][nn][q * 4 + 0]);
        o.y = f2bf(acc[m][nn][q * 4 + 1]);
        o.z = f2bf(acc[m][nn][q * 4 + 2]);
        o.w = f2bf(acc[m][nn][q * 4 + 3]);
        *(ushort4*)(out + obase + (size_t)px * 64 + ocb) = o;
      }
    }

  // ---- fused BN partial stats (sum & sumsq over this block's 256 px)
  float sv[2][16], qv[2][16];
#pragma unroll
  for (int m = 0; m < 2; ++m)
#pragma unroll
    for (int r = 0; r < 16; ++r) {
      const float a0 = acc[m][0][r], a1 = acc[m][1][r];
      sv[m][r] = a0 + a1;
      qv[m][r] = a0 * a0 + a1 * a1;
    }
#pragma unroll
  for (int st = 1; st <= 16; st <<= 1)
#pragma unroll
    for (int m = 0; m < 2; ++m)
#pragma unroll
      for (int r = 0; r < 16; ++r) {
        sv[m][r] += __shfl_xor(sv[m][r], st);
        qv[m][r] += __shfl_xor(qv[m][r], st);
      }
#pragma unroll
  for (int r = 0; r < 16; ++r)
    if ((lane & 31) == r) {
#pragma unroll
      for (int m = 0; m < 2; ++m) {
        const int oc = m * 32 + (r & 3) + 8 * (r >> 2) + 4 * (lane >> 5);
        s_red[0][wv][oc] = sv[m][r];
        s_red[1][wv][oc] = qv[m][r];
      }
    }
  __syncthreads();
  if (t < 64) {
    psum[(size_t)b * 64 + t] = s_red[0][0][t] + s_red[0][1][t] + s_red[0][2][t] + s_red[0][3][t];
    psq[(size_t)b * 64 + t]  = s_red[1][0][t] + s_red[1][1][t] + s_red[1][2][t] + s_red[1][3][t];
  }
}

// ---- BN stats over padded buffer (conv1 only)
__global__ __launch_bounds__(256)
void k_bnstats_p(const unsigned short* __restrict__ y, float* __restrict__ psum,
                 float* __restrict__ psq) {
  __shared__ float ls[256], lq[256];
  const int b = blockIdx.x, t = threadIdx.x;
  const int c = t & 63, sub = t >> 6;
  float sum = 0.f, sq = 0.f;
  for (int j = sub; j < 512; j += 4) {
    const int px = b * 512 + j;
    const int n = px >> 16, hh = (px >> 8) & 255, ww = px & 255;
    const float v = __uint_as_float(
        ((unsigned)y[(padpx(n, hh, ww)) * 64 + c]) << 16);
    sum += v; sq += v * v;
  }
  ls[t] = sum; lq[t] = sq;
  __syncthreads();
  if (t < 128) { ls[t] += ls[t + 128]; lq[t] += lq[t + 128]; }
  __syncthreads();
  if (t < 64) {
    psum[(size_t)b * 64 + t] = ls[t] + ls[t + 64];
    psq[(size_t)b * 64 + t]  = lq[t] + lq[t + 64];
  }
}

// ---- BN stats finalize: reduce nb partials -> per-channel scale/shift
__global__ __launch_bounds__(256)
void k_bnfin(const float* __restrict__ psum, const float* __restrict__ psq,
             const float* __restrict__ g, const float* __restrict__ be,
             float* __restrict__ bnp, int nb) {
  __shared__ float s1[256], s2[256];
  const int t = threadIdx.x;
  const int c = t & 63, sub = t >> 6;
  float s = 0.f, q = 0.f;
  for (int b = sub; b < nb; b += 4) {
    s += psum[(size_t)b * 64 + c];
    q += psq[(size_t)b * 64 + c];
  }
  s1[t] = s; s2[t] = q;
  __syncthreads();
  if (t < 64) {
    s = s1[t] + s1[t + 64] + s1[t + 128] + s1[t + 192];
    q = s2[t] + s2[t + 64] + s2[t + 128] + s2[t + 192];
    const float m = s / PTOTF;
    const float var = q / PTOTF - m * m;
    const float sc = g[t] * rsqrtf(var + 1e-5f);
    bnp[t] = sc;
    bnp[64 + t] = be[t] - m * sc;
  }
}

// ---- elementwise on padded buffers: a = celu(y*sc+sh) [+ a]
template<int RES>
__global__ __launch_bounds__(256)
void k_apply(const unsigned short* __restrict__ y, const float* __restrict__ bnp,
             unsigned short* __restrict__ a) {
  const size_t gid = (size_t)blockIdx.x * 256 + threadIdx.x;
  const int px = (int)(gid >> 3);
  const int c0 = ((int)gid & 7) * 8;
  const int n = px >> 16, hh = (px >> 8) & 255, ww = px & 255;
  const size_t i = padpx(n, hh, ww) * 64 + c0;
  float v[8];
  unpack8(*(const uint4*)(y + i), v);
  const float4 sa = *(const float4*)(bnp + c0);
  const float4 sb = *(const float4*)(bnp + c0 + 4);
  const float4 ha = *(const float4*)(bnp + 64 + c0);
  const float4 hb = *(const float4*)(bnp + 64 + c0 + 4);
  const float sc[8] = {sa.x, sa.y, sa.z, sa.w, sb.x, sb.y, sb.z, sb.w};
  const float sh[8] = {ha.x, ha.y, ha.z, ha.w, hb.x, hb.y, hb.z, hb.w};
  float r[8];
#pragma unroll
  for (int q = 0; q < 8; ++q) r[q] = celuf(v[q] * sc[q] + sh[q]);
  if (RES) {
    float av[8];
    unpack8(*(const uint4*)(a + i), av);
#pragma unroll
    for (int q = 0; q < 8; ++q) r[q] += av[q];
  }
  uint4 o;
  o.x = (unsigned)f2bf(r[0]) | ((unsigned)f2bf(r[1]) << 16);
  o.y = (unsigned)f2bf(r[2]) | ((unsigned)f2bf(r[3]) << 16);
  o.z = (unsigned)f2bf(r[4]) | ((unsigned)f2bf(r[5]) << 16);
  o.w = (unsigned)f2bf(r[6]) | ((unsigned)f2bf(r[7]) << 16);
  *(uint4*)(a + i) = o;
}

// ---- last conv 64->3 + bias + celu + x, padded bf16 in, NCHW fp32 out
__global__ __launch_bounds__(256)
void k_last(const unsigned short* __restrict__ a, const float* __restrict__ x,
            const float* __restrict__ wl, const float* __restrict__ b2,
            float* __restrict__ outp) {
  __shared__ float wsm[2304];  // [9][64][4]
  for (int j = threadIdx.x; j < 2304; j += 256) wsm[j] = wl[j];
  __syncthreads();
  const int px = blockIdx.x * 256 + threadIdx.x;
  const int n = px >> 16, rem = px & 65535, h = rem >> 8, w = rem & 255;
  float a0 = 0.f, a1 = 0.f, a2 = 0.f;
#pragma unroll
  for (int dh = 0; dh < 3; ++dh)
#pragma unroll
    for (int dw = 0; dw < 3; ++dw) {
      const uint4* p = (const uint4*)(a + (((size_t)n * 258 + h + dh) * 258 + (w + dw)) * 64);
      const float* wt = &wsm[(dh * 3 + dw) * 256];
#pragma unroll
      for (int iv = 0; iv < 8; ++iv) {
        float v[8];
        unpack8(p[iv], v);
#pragma unroll
        for (int q = 0; q < 8; ++q) {
          const float* wr = &wt[(iv * 8 + q) * 4];
          a0 += v[q] * wr[0];
          a1 += v[q] * wr[1];
          a2 += v[q] * wr[2];
        }
      }
    }
  const size_t ob = (size_t)n * 3 * HW + ((size_t)h << 8) + w;
  outp[ob]          = celuf(a0 + b2[0]) + x[ob];
  outp[ob + HW]     = celuf(a1 + b2[1]) + x[ob + HW];
  outp[ob + 2 * HW] = celuf(a2 + b2[2]) + x[ob + 2 * HW];
}

extern "C" void kernel_launch(void* const* d_in, const int* in_sizes, int n_in,
                              void* d_out, int out_size, void* d_ws, size_t ws_size,
                              hipStream_t stream) {
  const float* x   = (const float*)d_in[0];
  const float* w1  = (const float*)d_in[1];
  // d_in[2] = b1 (cancels under BN)
  const float* g1  = (const float*)d_in[3];
  const float* be1 = (const float*)d_in[4];
  const float* bw  = (const float*)d_in[5];
  // d_in[6] = bb (cancels under BN)
  const float* bg  = (const float*)d_in[7];
  const float* bbe = (const float*)d_in[8];
  const float* w2  = (const float*)d_in[9];
  const float* b2  = (const float*)d_in[10];
  float* out = (float*)d_out;

  const size_t PADBUF = (size_t)8 * 258 * 258 * 64 * 2;  // bytes
  size_t off = 0;
  auto alloc = [&](size_t bytes) {
    size_t cur = off;
    off += (bytes + 255) & ~(size_t)255;
    return cur;
  };
  const size_t oA   = alloc(PADBUF);
  const size_t oB   = alloc(PADBUF);
  const size_t oC   = alloc(PADBUF);
  const size_t oW1  = alloc(4608 * 4);
  const size_t oWM  = alloc((size_t)6 * 36864 * 2);  // bf16 swizzled
  const size_t oWL  = alloc(2304 * 4);
  const size_t oMS  = alloc(48 * 4);
  const size_t oBNP = alloc(7 * 128 * 4);
  const size_t oPS  = alloc((size_t)2048 * 64 * 4);
  const size_t oPQ  = alloc((size_t)2048 * 64 * 4);
  if (off > ws_size) return;

  char* wsb = (char*)d_ws;
  unsigned short* bufA = (unsigned short*)(wsb + oA);
  unsigned short* bufB = (unsigned short*)(wsb + oB);
  unsigned short* bufC = (unsigned short*)(wsb + oC);
  float* wt1 = (float*)(wsb + oW1);
  unsigned short* wtm = (unsigned short*)(wsb + oWM);
  float* wtl = (float*)(wsb + oWL);
  float* ms  = (float*)(wsb + oMS);
  float* bnp = (float*)(wsb + oBNP);
  float* psum = (float*)(wsb + oPS);
  float* psq  = (float*)(wsb + oPQ);

  k_padzero<<<97, 256, 0, stream>>>(bufA, bufB, bufC);
  k_wt<<<8, 256, 0, stream>>>(w1, wt1, 64, 6, 8, 64);
  k_wtm<<<864, 256, 0, stream>>>(bw, wtm);
  k_wt<<<8, 256, 0, stream>>>(w2, wtl, 3, 64, 64, 4);
  k_inorm<<<24, 256, 0, stream>>>(x, ms);

  // conv1 (6->64) -> raw bufB (padded)
  k_conv1<<<8192, 256, 0, stream>>>(x, ms, wt1, bufB);
  k_bnstats_p<<<1024, 256, 0, stream>>>(bufB, psum, psq);
  k_bnfin<<<1, 256, 0, stream>>>(psum, psq, g1, be1, bnp, 1024);
  k_apply<0><<<16384, 256, 0, stream>>>(bufB, bnp, bufA);

  for (int i = 0; i < 3; ++i) {
    const int s1 = 1 + 2 * i, s2 = 2 + 2 * i;
    k_mconv<1><<<2048, 256, 0, stream>>>(bufA, nullptr,
        wtm + (size_t)(2 * i) * 36864, bufB, psum, psq);
    k_bnfin<<<1, 256, 0, stream>>>(psum, psq, bg + (size_t)(2 * i) * 64,
        bbe + (size_t)(2 * i) * 64, bnp + (size_t)s1 * 128, 2048);
    k_mconv<2><<<2048, 256, 0, stream>>>(bufB, bnp + (size_t)s1 * 128,
        wtm + (size_t)(2 * i + 1) * 36864, bufC, psum, psq);
    k_bnfin<<<1, 256, 0, stream>>>(psum, psq, bg + (size_t)(2 * i + 1) * 64,
        bbe + (size_t)(2 * i + 1) * 64, bnp + (size_t)s2 * 128, 2048);
    k_apply<1><<<16384, 256, 0, stream>>>(bufC, bnp + (size_t)s2 * 128, bufA);
  }

  k_last<<<2048, 256, 0, stream>>>(bufA, x, wtl, b2, out);
}

// Round 6
// 1973.605 us; speedup vs baseline: 3.2556x; 3.2556x over previous
//
#include <hip/hip_runtime.h>
#include <cstdint>
#include <cstddef>

#define DEVI __device__ __forceinline__

static constexpr int HW = 65536;          // 256*256
static constexpr float PTOTF = 524288.0f; // 8*256*256

typedef __attribute__((ext_vector_type(8))) short bfx8;
typedef __attribute__((ext_vector_type(16))) float fx16;

DEVI unsigned short f2bf(float f) {
  unsigned int x = __float_as_uint(f);
  x += 0x7fffu + ((x >> 16) & 1u);
  return (unsigned short)(x >> 16);
}
DEVI float celuf(float v) { return v > 0.0f ? v : expm1f(v); }

DEVI void unpack8(const uint4 u, float* v) {
  v[0] = __uint_as_float(u.x << 16); v[1] = __uint_as_float(u.x & 0xffff0000u);
  v[2] = __uint_as_float(u.y << 16); v[3] = __uint_as_float(u.y & 0xffff0000u);
  v[4] = __uint_as_float(u.z << 16); v[5] = __uint_as_float(u.z & 0xffff0000u);
  v[6] = __uint_as_float(u.w << 16); v[7] = __uint_as_float(u.w & 0xffff0000u);
}

// padded pixel base index: interior (n,h,w) -> element offset/64
DEVI size_t padpx(int n, int h, int w) {
  return ((size_t)n * 258 + (h + 1)) * 258 + (w + 1);
}

// ---- weight transform: src [OC][IC][3][3] -> dst [9][ICP][OCP] fp32 (conv1/last)
__global__ void k_wt(const float* __restrict__ w, float* __restrict__ dst,
                     int OC, int IC, int ICP, int OCP) {
  const int tot = 9 * ICP * OCP;
  for (int idx = blockIdx.x * blockDim.x + threadIdx.x; idx < tot;
       idx += gridDim.x * blockDim.x) {
    const int tap = idx / (ICP * OCP);
    const int r = idx - tap * (ICP * OCP);
    const int ic = r / OCP, oc = r - ic * OCP;
    dst[idx] = (ic < IC && oc < OC) ? w[(oc * IC + ic) * 9 + tap] : 0.0f;
  }
}

// ---- main-weight transform: bw [6][64][64][3][3] fp32 -> [6][9][64][64] bf16,
// ic-chunk XOR-swizzled so linear LDS staging yields conflict-free frag reads.
__global__ void k_wtm(const float* __restrict__ w, unsigned short* __restrict__ dst) {
  const int idx = blockIdx.x * 256 + threadIdx.x;
  if (idx >= 6 * 36864) return;
  const int cv = idx / 36864, r = idx - cv * 36864;
  const int tap = r >> 12, rr = r & 4095, oc = rr >> 6, ic = rr & 63;
  const float v = w[((size_t)cv * 4096 + oc * 64 + ic) * 9 + tap];
  const int dic = ((((ic >> 3) ^ (oc & 7)) << 3) | (ic & 7));
  dst[(size_t)cv * 36864 + tap * 4096 + oc * 64 + dic] = f2bf(v);
}

// ---- zero the 1-px pad border of the three padded NHWC buffers
__global__ void k_padzero(unsigned short* a, unsigned short* b, unsigned short* c) {
  const int id = blockIdx.x * 256 + threadIdx.x;
  if (id >= 3 * 8 * 1028) return;
  const int buf = id / (8 * 1028), r = id - buf * (8 * 1028);
  const int n = r / 1028, k = r - n * 1028;
  int hp, wp;
  if (k < 258)      { hp = 0;           wp = k; }
  else if (k < 516) { hp = 257;         wp = k - 258; }
  else if (k < 772) { hp = k - 516 + 1; wp = 0; }
  else              { hp = k - 772 + 1; wp = 257; }
  unsigned short* p = (buf == 0 ? a : buf == 1 ? b : c) +
                      (((size_t)n * 258 + hp) * 258 + wp) * 64;
  const uint4 z = {0, 0, 0, 0};
#pragma unroll
  for (int q = 0; q < 8; ++q) ((uint4*)p)[q] = z;
}

// ---- instance norm stats: one block per (n,c)
__global__ __launch_bounds__(256)
void k_inorm(const float* __restrict__ x, float* __restrict__ ms) {
  __shared__ float s1[256], s2[256];
  const int b = blockIdx.x;
  const float4* p = (const float4*)(x + (size_t)b * HW);
  float sum = 0.f, sq = 0.f;
  for (int j = threadIdx.x; j < HW / 4; j += 256) {
    const float4 v = p[j];
    sum += v.x + v.y + v.z + v.w;
    sq  += v.x * v.x + v.y * v.y + v.z * v.z + v.w * v.w;
  }
  s1[threadIdx.x] = sum; s2[threadIdx.x] = sq;
  __syncthreads();
  for (int s = 128; s > 0; s >>= 1) {
    if ((int)threadIdx.x < s) {
      s1[threadIdx.x] += s1[threadIdx.x + s];
      s2[threadIdx.x] += s2[threadIdx.x + s];
    }
    __syncthreads();
  }
  if (threadIdx.x == 0) {
    const float m = s1[0] * (1.0f / HW);
    const float var = (s2[0] - s1[0] * s1[0] * (1.0f / HW)) * (1.0f / (HW - 1));
    ms[2 * b] = m;
    ms[2 * b + 1] = rsqrtf(var);
  }
}

// ---- conv1 (6->64), VALU path, writes PADDED raw bf16 output
__global__ __launch_bounds__(256)
void k_conv1(const float* __restrict__ x, const float* __restrict__ ms,
             const float* __restrict__ wt, unsigned short* __restrict__ out) {
  __shared__ float in_s[3 * 66 * 9];
  __shared__ float w_s[9 * 8 * 64];

  const int t = threadIdx.x;
  const int b = blockIdx.x;
  const int n = b >> 10;
  const int h = (b >> 2) & 255;
  const int w0 = (b & 3) << 6;

  const float m0 = ms[6 * n + 0], r0 = ms[6 * n + 1];
  const float m1 = ms[6 * n + 2], r1 = ms[6 * n + 3];
  const float m2 = ms[6 * n + 4], r2 = ms[6 * n + 5];

  const int oc0 = (t & 15) * 4;
  const int px0 = (t >> 4) * 4;
  float acc[4][4] = {{0.f}};

  {  // stage weights [9][8][64]
    const float4* wsrc = (const float4*)wt;
    for (int j4 = t; j4 < 1152; j4 += 256) ((float4*)w_s)[j4] = wsrc[j4];
  }
  if (t < 198) {  // stage input tile
    const int dh = t / 66, px = t - dh * 66;
    const int gh = h + dh - 1, gw = w0 + px - 1;
    const bool ok = ((unsigned)gh < 256u) && ((unsigned)gw < 256u);
    float v[8];
    if (ok) {
      const float* xp = x + (size_t)n * 3 * HW + gh * 256 + gw;
      const float a0 = xp[0], a1 = xp[HW], a2 = xp[2 * HW];
      v[0] = a0; v[1] = a1; v[2] = a2;
      v[3] = (a0 - m0) * r0; v[4] = (a1 - m1) * r1; v[5] = (a2 - m2) * r2;
      v[6] = 0.f; v[7] = 0.f;
    } else {
#pragma unroll
      for (int q = 0; q < 8; ++q) v[q] = 0.f;
    }
    float* d = &in_s[(dh * 66 + px) * 9];
#pragma unroll
    for (int q = 0; q < 8; ++q) d[q] = v[q];
  }
  __syncthreads();
#pragma unroll
  for (int i = 0; i < 8; ++i) {
    float xv[3][6];
#pragma unroll
    for (int dh = 0; dh < 3; ++dh)
#pragma unroll
      for (int j = 0; j < 6; ++j)
        xv[dh][j] = in_s[(dh * 66 + px0 + j) * 9 + i];
#pragma unroll
    for (int dh = 0; dh < 3; ++dh)
#pragma unroll
      for (int dw = 0; dw < 3; ++dw) {
        const float4 wv = *(const float4*)&w_s[((dh * 3 + dw) * 8 + i) * 64 + oc0];
#pragma unroll
        for (int p = 0; p < 4; ++p) {
          const float xin = xv[dh][p + dw];
          acc[p][0] += xin * wv.x;
          acc[p][1] += xin * wv.y;
          acc[p][2] += xin * wv.z;
          acc[p][3] += xin * wv.w;
        }
      }
  }
  unsigned short* ob = out + (((size_t)n * 258 + (h + 1)) * 258 + (w0 + 1)) * 64;
#pragma unroll
  for (int p = 0; p < 4; ++p) {
    ushort4 o;
    o.x = f2bf(acc[p][0]); o.y = f2bf(acc[p][1]);
    o.z = f2bf(acc[p][2]); o.w = f2bf(acc[p][3]);
    *(ushort4*)(ob + (size_t)(px0 + p) * 64 + oc0) = o;
  }
}

// ---- MFMA implicit-GEMM 3x3 conv 64->64, padded bf16 NHWC in/out.
// MODE 1: input is activation (identity). MODE 2: input is raw; apply
// BN (scale/shift) + CELU at staging (pad positions forced to zero).
// Block: 4 rows x 64 px x 64 oc; wave wv owns row wv. D[oc][px] orientation.
// Fused BN partial stats -> psum/psq[block][64].
template<int MODE>
__global__ __launch_bounds__(256, 2)
void k_mconv(const unsigned short* __restrict__ in, const float* __restrict__ bnp,
             const unsigned short* __restrict__ wsw, unsigned short* __restrict__ out,
             float* __restrict__ psum, float* __restrict__ psq) {
  __shared__ __align__(16) unsigned short a_s[6 * 66 * 64];
  __shared__ __align__(16) unsigned short w_s[2][4096];
  __shared__ float s_red[2][4][64];
  __shared__ float s_sc[64], s_sh[64];

  const int t = threadIdx.x;
  const int lane = t & 63, wv = t >> 6;
  int b = blockIdx.x;
  b = (b & 7) * 256 + (b >> 3);  // XCD swizzle (2048 = 8*256, bijective)
  const int n  = b >> 8;
  const int h0 = ((b >> 2) & 63) * 4;
  const int w0 = (b & 3) * 64;

  if (MODE == 2) {
    if (t < 64) { s_sc[t] = bnp[t]; s_sh[t] = bnp[64 + t]; }
    __syncthreads();
  }

  // issue tap-0 weight loads (global layout pre-swizzled -> linear copy)
  const uint4* wsrc0 = (const uint4*)wsw;
  const uint4 wz0 = wsrc0[t], wz1 = wsrc0[t + 256];

  // ---- stage A tile [6 rows][66 px][64 ic], XOR-swizzled (3168 x 16B chunks)
  const size_t ibase = ((size_t)n * 258 + h0) * 258 + w0;
  for (int j = t; j < 3168; j += 256) {
    const int r  = j / 528;           // 528 = 66 px * 8 chunks
    const int c  = j - r * 528;
    const int px = c >> 3, sl = c & 7;
    uint4 u = *(const uint4*)(in + (ibase + (size_t)r * 258 + px) * 64 + sl * 8);
    if (MODE == 2) {
      const int hp = h0 + r, wp = w0 + px;
      const bool pad = (hp == 0) | (hp == 257) | (wp == 0) | (wp == 257);
      float vv[8];
      unpack8(u, vv);
#pragma unroll
      for (int q = 0; q < 8; ++q) {
        const float z = vv[q] * s_sc[sl * 8 + q] + s_sh[sl * 8 + q];
        vv[q] = pad ? 0.f : celuf(z);
      }
      uint4 o;
      o.x = (unsigned)f2bf(vv[0]) | ((unsigned)f2bf(vv[1]) << 16);
      o.y = (unsigned)f2bf(vv[2]) | ((unsigned)f2bf(vv[3]) << 16);
      o.z = (unsigned)f2bf(vv[4]) | ((unsigned)f2bf(vv[5]) << 16);
      o.w = (unsigned)f2bf(vv[6]) | ((unsigned)f2bf(vv[7]) << 16);
      u = o;
    }
    const int R = r * 66 + px;
    *(uint4*)((char*)a_s + (size_t)R * 128 + ((sl ^ (R & 7)) << 4)) = u;
  }
  ((uint4*)w_s[0])[t] = wz0;
  ((uint4*)w_s[0])[t + 256] = wz1;
  __syncthreads();

  fx16 acc[2][2] = {};

#pragma unroll
  for (int tap = 0; tap < 9; ++tap) {
    const int dh = tap / 3, dw = tap - dh * 3;
    uint4 wn0, wn1;
    if (tap < 8) {  // issue next-tap weight loads (written after compute)
      const uint4* wsrc = (const uint4*)(wsw + (size_t)(tap + 1) * 4096);
      wn0 = wsrc[t]; wn1 = wsrc[t + 256];
    }
    const unsigned short* wbuf = w_s[tap & 1];
    bfx8 af[2][4];
#pragma unroll
    for (int m = 0; m < 2; ++m)
#pragma unroll
      for (int ks = 0; ks < 4; ++ks) {
        const int oc = m * 32 + (lane & 31);
        const int sl = (ks * 2 + (lane >> 5)) ^ (oc & 7);
        af[m][ks] = *(const bfx8*)((const char*)wbuf + oc * 128 + (sl << 4));
      }
#pragma unroll
    for (int ks = 0; ks < 4; ++ks) {
      bfx8 bf[2];
#pragma unroll
      for (int nn = 0; nn < 2; ++nn) {
        const int px = nn * 32 + (lane & 31) + dw;
        const int R = (wv + dh) * 66 + px;
        const int sl = (ks * 2 + (lane >> 5)) ^ (R & 7);
        bf[nn] = *(const bfx8*)((const char*)a_s + (size_t)R * 128 + (sl << 4));
      }
#pragma unroll
      for (int m = 0; m < 2; ++m)
#pragma unroll
        for (int nn = 0; nn < 2; ++nn)
          acc[m][nn] = __builtin_amdgcn_mfma_f32_32x32x16_bf16(
              af[m][ks], bf[nn], acc[m][nn], 0, 0, 0);
    }
    if (tap < 8) {
      uint4* wdst = (uint4*)w_s[(tap + 1) & 1];
      wdst[t] = wn0; wdst[t + 256] = wn1;
    }
    __syncthreads();
  }

  // ---- store C: D rows = oc (4 contiguous per reg-quad), cols = px
  const size_t obase = (((size_t)n * 258 + (h0 + wv + 1)) * 258 + (w0 + 1)) * 64;
#pragma unroll
  for (int m = 0; m < 2; ++m)
#pragma unroll
    for (int nn = 0; nn < 2; ++nn) {
      const int px = nn * 32 + (lane & 31);
#pragma unroll
      for (int q = 0; q < 4; ++q) {
        const int ocb = m * 32 + q * 8 + 4 * (lane >> 5);
        ushort4 o;
        o.x = f2bf(acc[m][nn][q * 4 + 0]);
        o.y = f2bf(acc[m][nn][q * 4 + 1]);
        o.z = f2bf(acc[m][nn][q * 4 + 2]);
        o.w = f2bf(acc[m][nn][q * 4 + 3]);
        *(ushort4*)(out + obase + (size_t)px * 64 + ocb) = o;
      }
    }

  // ---- fused BN partial stats (sum & sumsq over this block's 256 px)
  float sv[2][16], qv[2][16];
#pragma unroll
  for (int m = 0; m < 2; ++m)
#pragma unroll
    for (int r = 0; r < 16; ++r) {
      const float a0 = acc[m][0][r], a1 = acc[m][1][r];
      sv[m][r] = a0 + a1;
      qv[m][r] = a0 * a0 + a1 * a1;
    }
#pragma unroll
  for (int st = 1; st <= 16; st <<= 1)
#pragma unroll
    for (int m = 0; m < 2; ++m)
#pragma unroll
      for (int r = 0; r < 16; ++r) {
        sv[m][r] += __shfl_xor(sv[m][r], st);
        qv[m][r] += __shfl_xor(qv[m][r], st);
      }
#pragma unroll
  for (int r = 0; r < 16; ++r)
    if ((lane & 31) == r) {
#pragma unroll
      for (int m = 0; m < 2; ++m) {
        const int oc = m * 32 + (r & 3) + 8 * (r >> 2) + 4 * (lane >> 5);
        s_red[0][wv][oc] = sv[m][r];
        s_red[1][wv][oc] = qv[m][r];
      }
    }
  __syncthreads();
  if (t < 64) {
    psum[(size_t)b * 64 + t] = s_red[0][0][t] + s_red[0][1][t] + s_red[0][2][t] + s_red[0][3][t];
    psq[(size_t)b * 64 + t]  = s_red[1][0][t] + s_red[1][1][t] + s_red[1][2][t] + s_red[1][3][t];
  }
}

// ---- BN stats over padded buffer (conv1 only)
__global__ __launch_bounds__(256)
void k_bnstats_p(const unsigned short* __restrict__ y, float* __restrict__ psum,
                 float* __restrict__ psq) {
  __shared__ float ls[256], lq[256];
  const int b = blockIdx.x, t = threadIdx.x;
  const int c = t & 63, sub = t >> 6;
  float sum = 0.f, sq = 0.f;
  for (int j = sub; j < 512; j += 4) {
    const int px = b * 512 + j;
    const int n = px >> 16, hh = (px >> 8) & 255, ww = px & 255;
    const float v = __uint_as_float(
        ((unsigned)y[(padpx(n, hh, ww)) * 64 + c]) << 16);
    sum += v; sq += v * v;
  }
  ls[t] = sum; lq[t] = sq;
  __syncthreads();
  if (t < 128) { ls[t] += ls[t + 128]; lq[t] += lq[t + 128]; }
  __syncthreads();
  if (t < 64) {
    psum[(size_t)b * 64 + t] = ls[t] + ls[t + 64];
    psq[(size_t)b * 64 + t]  = lq[t] + lq[t + 64];
  }
}

// ---- BN stats finalize: reduce nb partials -> per-channel scale/shift
__global__ __launch_bounds__(256)
void k_bnfin(const float* __restrict__ psum, const float* __restrict__ psq,
             const float* __restrict__ g, const float* __restrict__ be,
             float* __restrict__ bnp, int nb) {
  __shared__ float s1[256], s2[256];
  const int t = threadIdx.x;
  const int c = t & 63, sub = t >> 6;
  float s = 0.f, q = 0.f;
  for (int b = sub; b < nb; b += 4) {
    s += psum[(size_t)b * 64 + c];
    q += psq[(size_t)b * 64 + c];
  }
  s1[t] = s; s2[t] = q;
  __syncthreads();
  if (t < 64) {
    s = s1[t] + s1[t + 64] + s1[t + 128] + s1[t + 192];
    q = s2[t] + s2[t + 64] + s2[t + 128] + s2[t + 192];
    const float m = s / PTOTF;
    const float var = q / PTOTF - m * m;
    const float sc = g[t] * rsqrtf(var + 1e-5f);
    bnp[t] = sc;
    bnp[64 + t] = be[t] - m * sc;
  }
}

// ---- elementwise on padded buffers: a = celu(y*sc+sh) [+ a]
template<int RES>
__global__ __launch_bounds__(256)
void k_apply(const unsigned short* __restrict__ y, const float* __restrict__ bnp,
             unsigned short* __restrict__ a) {
  const size_t gid = (size_t)blockIdx.x * 256 + threadIdx.x;
  const int px = (int)(gid >> 3);
  const int c0 = ((int)gid & 7) * 8;
  const int n = px >> 16, hh = (px >> 8) & 255, ww = px & 255;
  const size_t i = padpx(n, hh, ww) * 64 + c0;
  float v[8];
  unpack8(*(const uint4*)(y + i), v);
  const float4 sa = *(const float4*)(bnp + c0);
  const float4 sb = *(const float4*)(bnp + c0 + 4);
  const float4 ha = *(const float4*)(bnp + 64 + c0);
  const float4 hb = *(const float4*)(bnp + 64 + c0 + 4);
  const float sc[8] = {sa.x, sa.y, sa.z, sa.w, sb.x, sb.y, sb.z, sb.w};
  const float sh[8] = {ha.x, ha.y, ha.z, ha.w, hb.x, hb.y, hb.z, hb.w};
  float r[8];
#pragma unroll
  for (int q = 0; q < 8; ++q) r[q] = celuf(v[q] * sc[q] + sh[q]);
  if (RES) {
    float av[8];
    unpack8(*(const uint4*)(a + i), av);
#pragma unroll
    for (int q = 0; q < 8; ++q) r[q] += av[q];
  }
  uint4 o;
  o.x = (unsigned)f2bf(r[0]) | ((unsigned)f2bf(r[1]) << 16);
  o.y = (unsigned)f2bf(r[2]) | ((unsigned)f2bf(r[3]) << 16);
  o.z = (unsigned)f2bf(r[4]) | ((unsigned)f2bf(r[5]) << 16);
  o.w = (unsigned)f2bf(r[6]) | ((unsigned)f2bf(r[7]) << 16);
  *(uint4*)(a + i) = o;
}

// ---- last conv 64->3 + bias + celu + x. LDS-tiled, low-VGPR.
// Block: one 64-px row segment. 192 threads = 64 px x 3 oc.
// Input tile [3][66][64] bf16 staged XOR-swizzled; weights [3 oc][576] f32
// (wave-uniform broadcast reads). Tap loop kept rolled to bound registers.
__global__ __launch_bounds__(192)
void k_last(const unsigned short* __restrict__ a, const float* __restrict__ x,
            const float* __restrict__ wl, const float* __restrict__ b2,
            float* __restrict__ outp) {
  __shared__ __align__(16) unsigned short in_s[198 * 64];  // swizzled, 25344 B
  __shared__ float wsm[3][576];                             // [oc][tap*64+ic]

  const int t = threadIdx.x;
  const int b = blockIdx.x;
  const int n = b >> 10;
  const int h = (b >> 2) & 255;
  const int w0 = (b & 3) << 6;

  // stage weights: wl is [9][64][4] -> wsm[oc][tap*64+ic]
  for (int j = t; j < 1728; j += 192) {
    const int oc = j / 576, k = j - oc * 576;
    const int tap = k >> 6, ic = k & 63;
    wsm[oc][k] = wl[tap * 256 + ic * 4 + oc];
  }
  // stage input tile: rows h-1..h+1 (padded h..h+2), px w0-1..w0+64
  for (int j = t; j < 1584; j += 192) {  // 198 rows x 8 chunks
    const int r = j >> 3, sl = j & 7;
    const int dh = r / 66, px = r - dh * 66;
    const uint4 u = *(const uint4*)(a +
        (((size_t)n * 258 + (h + dh)) * 258 + (w0 + px)) * 64 + sl * 8);
    *(uint4*)((char*)in_s + (size_t)r * 128 + ((sl ^ (r & 7)) << 4)) = u;
  }
  __syncthreads();

  const int px = t & 63;
  const int oc = t >> 6;  // 0..2
  float acc = 0.f;
#pragma unroll 1
  for (int tap = 0; tap < 9; ++tap) {
    const int dh = tap / 3, dw = tap - dh * 3;
    const int R = dh * 66 + px + dw;
    const float* wrow = &wsm[oc][tap * 64];
#pragma unroll
    for (int sl = 0; sl < 8; ++sl) {
      const uint4 u = *(const uint4*)((const char*)in_s +
          (size_t)R * 128 + ((sl ^ (R & 7)) << 4));
      float v[8];
      unpack8(u, v);
      const float4 wa = *(const float4*)(wrow + sl * 8);
      const float4 wb = *(const float4*)(wrow + sl * 8 + 4);
      acc += v[0] * wa.x + v[1] * wa.y + v[2] * wa.z + v[3] * wa.w +
             v[4] * wb.x + v[5] * wb.y + v[6] * wb.z + v[7] * wb.w;
    }
  }
  const size_t ob = (size_t)n * 3 * HW + (size_t)oc * HW + ((size_t)h << 8) + w0 + px;
  outp[ob] = celuf(acc + b2[oc]) + x[ob];
}

extern "C" void kernel_launch(void* const* d_in, const int* in_sizes, int n_in,
                              void* d_out, int out_size, void* d_ws, size_t ws_size,
                              hipStream_t stream) {
  const float* x   = (const float*)d_in[0];
  const float* w1  = (const float*)d_in[1];
  // d_in[2] = b1 (cancels under BN)
  const float* g1  = (const float*)d_in[3];
  const float* be1 = (const float*)d_in[4];
  const float* bw  = (const float*)d_in[5];
  // d_in[6] = bb (cancels under BN)
  const float* bg  = (const float*)d_in[7];
  const float* bbe = (const float*)d_in[8];
  const float* w2  = (const float*)d_in[9];
  const float* b2  = (const float*)d_in[10];
  float* out = (float*)d_out;

  const size_t PADBUF = (size_t)8 * 258 * 258 * 64 * 2;  // bytes
  size_t off = 0;
  auto alloc = [&](size_t bytes) {
    size_t cur = off;
    off += (bytes + 255) & ~(size_t)255;
    return cur;
  };
  const size_t oA   = alloc(PADBUF);
  const size_t oB   = alloc(PADBUF);
  const size_t oC   = alloc(PADBUF);
  const size_t oW1  = alloc(4608 * 4);
  const size_t oWM  = alloc((size_t)6 * 36864 * 2);  // bf16 swizzled
  const size_t oWL  = alloc(2304 * 4);
  const size_t oMS  = alloc(48 * 4);
  const size_t oBNP = alloc(7 * 128 * 4);
  const size_t oPS  = alloc((size_t)2048 * 64 * 4);
  const size_t oPQ  = alloc((size_t)2048 * 64 * 4);
  if (off > ws_size) return;

  char* wsb = (char*)d_ws;
  unsigned short* bufA = (unsigned short*)(wsb + oA);
  unsigned short* bufB = (unsigned short*)(wsb + oB);
  unsigned short* bufC = (unsigned short*)(wsb + oC);
  float* wt1 = (float*)(wsb + oW1);
  unsigned short* wtm = (unsigned short*)(wsb + oWM);
  float* wtl = (float*)(wsb + oWL);
  float* ms  = (float*)(wsb + oMS);
  float* bnp = (float*)(wsb + oBNP);
  float* psum = (float*)(wsb + oPS);
  float* psq  = (float*)(wsb + oPQ);

  k_padzero<<<97, 256, 0, stream>>>(bufA, bufB, bufC);
  k_wt<<<8, 256, 0, stream>>>(w1, wt1, 64, 6, 8, 64);
  k_wtm<<<864, 256, 0, stream>>>(bw, wtm);
  k_wt<<<8, 256, 0, stream>>>(w2, wtl, 3, 64, 64, 4);
  k_inorm<<<24, 256, 0, stream>>>(x, ms);

  // conv1 (6->64) -> raw bufB (padded)
  k_conv1<<<8192, 256, 0, stream>>>(x, ms, wt1, bufB);
  k_bnstats_p<<<1024, 256, 0, stream>>>(bufB, psum, psq);
  k_bnfin<<<1, 256, 0, stream>>>(psum, psq, g1, be1, bnp, 1024);
  k_apply<0><<<16384, 256, 0, stream>>>(bufB, bnp, bufA);

  for (int i = 0; i < 3; ++i) {
    const int s1 = 1 + 2 * i, s2 = 2 + 2 * i;
    k_mconv<1><<<2048, 256, 0, stream>>>(bufA, nullptr,
        wtm + (size_t)(2 * i) * 36864, bufB, psum, psq);
    k_bnfin<<<1, 256, 0, stream>>>(psum, psq, bg + (size_t)(2 * i) * 64,
        bbe + (size_t)(2 * i) * 64, bnp + (size_t)s1 * 128, 2048);
    k_mconv<2><<<2048, 256, 0, stream>>>(bufB, bnp + (size_t)s1 * 128,
        wtm + (size_t)(2 * i + 1) * 36864, bufC, psum, psq);
    k_bnfin<<<1, 256, 0, stream>>>(psum, psq, bg + (size_t)(2 * i + 1) * 64,
        bbe + (size_t)(2 * i + 1) * 64, bnp + (size_t)s2 * 128, 2048);
    k_apply<1><<<16384, 256, 0, stream>>>(bufC, bnp + (size_t)s2 * 128, bufA);
  }

  k_last<<<8192, 192, 0, stream>>>(bufA, x, wtl, b2, out);
}

// Round 7
// 1114.478 us; speedup vs baseline: 5.7653x; 1.7709x over previous
//
#include <hip/hip_runtime.h>
#include <cstdint>
#include <cstddef>

#define DEVI __device__ __forceinline__

static constexpr int HW = 65536;          // 256*256
static constexpr float PTOTF = 524288.0f; // 8*256*256
static constexpr int NPB = 8192;          // partial-stats stride (max blocks)

typedef __attribute__((ext_vector_type(8))) short bfx8;
typedef __attribute__((ext_vector_type(16))) float fx16;

DEVI unsigned short f2bf(float f) {
  unsigned int x = __float_as_uint(f);
  x += 0x7fffu + ((x >> 16) & 1u);
  return (unsigned short)(x >> 16);
}
DEVI float celuf(float v) { return v > 0.0f ? v : expm1f(v); }

DEVI void unpack8(const uint4 u, float* v) {
  v[0] = __uint_as_float(u.x << 16); v[1] = __uint_as_float(u.x & 0xffff0000u);
  v[2] = __uint_as_float(u.y << 16); v[3] = __uint_as_float(u.y & 0xffff0000u);
  v[4] = __uint_as_float(u.z << 16); v[5] = __uint_as_float(u.z & 0xffff0000u);
  v[6] = __uint_as_float(u.w << 16); v[7] = __uint_as_float(u.w & 0xffff0000u);
}

// padded pixel base index: interior (n,h,w) -> element offset/64
DEVI size_t padpx(int n, int h, int w) {
  return ((size_t)n * 258 + (h + 1)) * 258 + (w + 1);
}

// ---- weight transform: src [OC][IC][3][3] -> dst [9][ICP][OCP] fp32 (conv1/last)
__global__ void k_wt(const float* __restrict__ w, float* __restrict__ dst,
                     int OC, int IC, int ICP, int OCP) {
  const int tot = 9 * ICP * OCP;
  for (int idx = blockIdx.x * blockDim.x + threadIdx.x; idx < tot;
       idx += gridDim.x * blockDim.x) {
    const int tap = idx / (ICP * OCP);
    const int r = idx - tap * (ICP * OCP);
    const int ic = r / OCP, oc = r - ic * OCP;
    dst[idx] = (ic < IC && oc < OC) ? w[(oc * IC + ic) * 9 + tap] : 0.0f;
  }
}

// ---- main-weight transform: bw [6][64][64][3][3] fp32 -> [6][9][64][64] bf16,
// ic-chunk XOR-swizzled so linear LDS staging yields conflict-free frag reads.
__global__ void k_wtm(const float* __restrict__ w, unsigned short* __restrict__ dst) {
  const int idx = blockIdx.x * 256 + threadIdx.x;
  if (idx >= 6 * 36864) return;
  const int cv = idx / 36864, r = idx - cv * 36864;
  const int tap = r >> 12, rr = r & 4095, oc = rr >> 6, ic = rr & 63;
  const float v = w[((size_t)cv * 4096 + oc * 64 + ic) * 9 + tap];
  const int dic = ((((ic >> 3) ^ (oc & 7)) << 3) | (ic & 7));
  dst[(size_t)cv * 36864 + tap * 4096 + oc * 64 + dic] = f2bf(v);
}

// ---- zero the 1-px pad border of the three padded NHWC buffers
__global__ void k_padzero(unsigned short* a, unsigned short* b, unsigned short* c) {
  const int id = blockIdx.x * 256 + threadIdx.x;
  if (id >= 3 * 8 * 1028) return;
  const int buf = id / (8 * 1028), r = id - buf * (8 * 1028);
  const int n = r / 1028, k = r - n * 1028;
  int hp, wp;
  if (k < 258)      { hp = 0;           wp = k; }
  else if (k < 516) { hp = 257;         wp = k - 258; }
  else if (k < 772) { hp = k - 516 + 1; wp = 0; }
  else              { hp = k - 772 + 1; wp = 257; }
  unsigned short* p = (buf == 0 ? a : buf == 1 ? b : c) +
                      (((size_t)n * 258 + hp) * 258 + wp) * 64;
  const uint4 z = {0, 0, 0, 0};
#pragma unroll
  for (int q = 0; q < 8; ++q) ((uint4*)p)[q] = z;
}

// ---- instance norm stats: one block per (n,c)
__global__ __launch_bounds__(256)
void k_inorm(const float* __restrict__ x, float* __restrict__ ms) {
  __shared__ float s1[256], s2[256];
  const int b = blockIdx.x;
  const float4* p = (const float4*)(x + (size_t)b * HW);
  float sum = 0.f, sq = 0.f;
  for (int j = threadIdx.x; j < HW / 4; j += 256) {
    const float4 v = p[j];
    sum += v.x + v.y + v.z + v.w;
    sq  += v.x * v.x + v.y * v.y + v.z * v.z + v.w * v.w;
  }
  s1[threadIdx.x] = sum; s2[threadIdx.x] = sq;
  __syncthreads();
  for (int s = 128; s > 0; s >>= 1) {
    if ((int)threadIdx.x < s) {
      s1[threadIdx.x] += s1[threadIdx.x + s];
      s2[threadIdx.x] += s2[threadIdx.x + s];
    }
    __syncthreads();
  }
  if (threadIdx.x == 0) {
    const float m = s1[0] * (1.0f / HW);
    const float var = (s2[0] - s1[0] * s1[0] * (1.0f / HW)) * (1.0f / (HW - 1));
    ms[2 * b] = m;
    ms[2 * b + 1] = rsqrtf(var);
  }
}

// ---- conv1 (6->64), VALU path, padded raw bf16 out + fused BN partial stats
__global__ __launch_bounds__(256)
void k_conv1(const float* __restrict__ x, const float* __restrict__ ms,
             const float* __restrict__ wt, unsigned short* __restrict__ out,
             float* __restrict__ psum, float* __restrict__ psq) {
  __shared__ float in_s[3 * 66 * 9];
  __shared__ float w_s[9 * 8 * 64];
  __shared__ float red0[16][64], red1[16][64];

  const int t = threadIdx.x;
  const int b = blockIdx.x;
  const int n = b >> 10;
  const int h = (b >> 2) & 255;
  const int w0 = (b & 3) << 6;

  const float m0 = ms[6 * n + 0], r0 = ms[6 * n + 1];
  const float m1 = ms[6 * n + 2], r1 = ms[6 * n + 3];
  const float m2 = ms[6 * n + 4], r2 = ms[6 * n + 5];

  const int oc0 = (t & 15) * 4;
  const int px0 = (t >> 4) * 4;
  float acc[4][4] = {{0.f}};

  {  // stage weights [9][8][64]
    const float4* wsrc = (const float4*)wt;
    for (int j4 = t; j4 < 1152; j4 += 256) ((float4*)w_s)[j4] = wsrc[j4];
  }
  if (t < 198) {  // stage input tile
    const int dh = t / 66, px = t - dh * 66;
    const int gh = h + dh - 1, gw = w0 + px - 1;
    const bool ok = ((unsigned)gh < 256u) && ((unsigned)gw < 256u);
    float v[8];
    if (ok) {
      const float* xp = x + (size_t)n * 3 * HW + gh * 256 + gw;
      const float a0 = xp[0], a1 = xp[HW], a2 = xp[2 * HW];
      v[0] = a0; v[1] = a1; v[2] = a2;
      v[3] = (a0 - m0) * r0; v[4] = (a1 - m1) * r1; v[5] = (a2 - m2) * r2;
      v[6] = 0.f; v[7] = 0.f;
    } else {
#pragma unroll
      for (int q = 0; q < 8; ++q) v[q] = 0.f;
    }
    float* d = &in_s[(dh * 66 + px) * 9];
#pragma unroll
    for (int q = 0; q < 8; ++q) d[q] = v[q];
  }
  __syncthreads();
#pragma unroll
  for (int i = 0; i < 8; ++i) {
    float xv[3][6];
#pragma unroll
    for (int dh = 0; dh < 3; ++dh)
#pragma unroll
      for (int j = 0; j < 6; ++j)
        xv[dh][j] = in_s[(dh * 66 + px0 + j) * 9 + i];
#pragma unroll
    for (int dh = 0; dh < 3; ++dh)
#pragma unroll
      for (int dw = 0; dw < 3; ++dw) {
        const float4 wv = *(const float4*)&w_s[((dh * 3 + dw) * 8 + i) * 64 + oc0];
#pragma unroll
        for (int p = 0; p < 4; ++p) {
          const float xin = xv[dh][p + dw];
          acc[p][0] += xin * wv.x;
          acc[p][1] += xin * wv.y;
          acc[p][2] += xin * wv.z;
          acc[p][3] += xin * wv.w;
        }
      }
  }
  unsigned short* ob = out + (((size_t)n * 258 + (h + 1)) * 258 + (w0 + 1)) * 64;
#pragma unroll
  for (int p = 0; p < 4; ++p) {
    ushort4 o;
    o.x = f2bf(acc[p][0]); o.y = f2bf(acc[p][1]);
    o.z = f2bf(acc[p][2]); o.w = f2bf(acc[p][3]);
    *(ushort4*)(ob + (size_t)(px0 + p) * 64 + oc0) = o;
  }
  // fused BN partial stats: reduce the 4 px of this thread, then 16 px-groups
#pragma unroll
  for (int q = 0; q < 4; ++q) {
    float s = 0.f, qv = 0.f;
#pragma unroll
    for (int p = 0; p < 4; ++p) { s += acc[p][q]; qv += acc[p][q] * acc[p][q]; }
    red0[t >> 4][oc0 + q] = s;
    red1[t >> 4][oc0 + q] = qv;
  }
  __syncthreads();
  if (t < 64) {
    float s = 0.f, qv = 0.f;
#pragma unroll
    for (int g2 = 0; g2 < 16; ++g2) { s += red0[g2][t]; qv += red1[g2][t]; }
    psum[(size_t)t * NPB + b] = s;
    psq[(size_t)t * NPB + b]  = qv;
  }
}

// ---- MFMA implicit-GEMM 3x3 conv 64->64, padded bf16 NHWC in/out.
// MODE 1: input is activation (identity). MODE 2: input is raw; apply
// BN (scale/shift) + CELU at staging (pad positions forced to zero).
// Block: 4 rows x 64 px x 64 oc; wave wv owns row wv. D[oc][px] orientation.
// Fused BN partial stats -> psum/psq[ch][block] (transposed, stride NPB).
template<int MODE>
__global__ __launch_bounds__(256, 2)
void k_mconv(const unsigned short* __restrict__ in, const float* __restrict__ bnp,
             const unsigned short* __restrict__ wsw, unsigned short* __restrict__ out,
             float* __restrict__ psum, float* __restrict__ psq) {
  __shared__ __align__(16) unsigned short a_s[6 * 66 * 64];
  __shared__ __align__(16) unsigned short w_s[2][4096];
  __shared__ float s_red[2][4][64];
  __shared__ float s_sc[64], s_sh[64];

  const int t = threadIdx.x;
  const int lane = t & 63, wv = t >> 6;
  int b = blockIdx.x;
  b = (b & 7) * 256 + (b >> 3);  // XCD swizzle (2048 = 8*256, bijective)
  const int n  = b >> 8;
  const int h0 = ((b >> 2) & 63) * 4;
  const int w0 = (b & 3) * 64;

  if (MODE == 2) {
    if (t < 64) { s_sc[t] = bnp[t]; s_sh[t] = bnp[64 + t]; }
    __syncthreads();
  }

  // issue tap-0 weight loads (global layout pre-swizzled -> linear copy)
  const uint4* wsrc0 = (const uint4*)wsw;
  const uint4 wz0 = wsrc0[t], wz1 = wsrc0[t + 256];

  // ---- stage A tile [6 rows][66 px][64 ic], XOR-swizzled (3168 x 16B chunks)
  const size_t ibase = ((size_t)n * 258 + h0) * 258 + w0;
  for (int j = t; j < 3168; j += 256) {
    const int r  = j / 528;           // 528 = 66 px * 8 chunks
    const int c  = j - r * 528;
    const int px = c >> 3, sl = c & 7;
    uint4 u = *(const uint4*)(in + (ibase + (size_t)r * 258 + px) * 64 + sl * 8);
    if (MODE == 2) {
      const int hp = h0 + r, wp = w0 + px;
      const bool pad = (hp == 0) | (hp == 257) | (wp == 0) | (wp == 257);
      float vv[8];
      unpack8(u, vv);
#pragma unroll
      for (int q = 0; q < 8; ++q) {
        const float z = vv[q] * s_sc[sl * 8 + q] + s_sh[sl * 8 + q];
        vv[q] = pad ? 0.f : celuf(z);
      }
      uint4 o;
      o.x = (unsigned)f2bf(vv[0]) | ((unsigned)f2bf(vv[1]) << 16);
      o.y = (unsigned)f2bf(vv[2]) | ((unsigned)f2bf(vv[3]) << 16);
      o.z = (unsigned)f2bf(vv[4]) | ((unsigned)f2bf(vv[5]) << 16);
      o.w = (unsigned)f2bf(vv[6]) | ((unsigned)f2bf(vv[7]) << 16);
      u = o;
    }
    const int R = r * 66 + px;
    *(uint4*)((char*)a_s + (size_t)R * 128 + ((sl ^ (R & 7)) << 4)) = u;
  }
  ((uint4*)w_s[0])[t] = wz0;
  ((uint4*)w_s[0])[t + 256] = wz1;
  __syncthreads();

  fx16 acc[2][2] = {};

#pragma unroll
  for (int tap = 0; tap < 9; ++tap) {
    const int dh = tap / 3, dw = tap - dh * 3;
    uint4 wn0, wn1;
    if (tap < 8) {  // issue next-tap weight loads (written after compute)
      const uint4* wsrc = (const uint4*)(wsw + (size_t)(tap + 1) * 4096);
      wn0 = wsrc[t]; wn1 = wsrc[t + 256];
    }
    const unsigned short* wbuf = w_s[tap & 1];
    bfx8 af[2][4];
#pragma unroll
    for (int m = 0; m < 2; ++m)
#pragma unroll
      for (int ks = 0; ks < 4; ++ks) {
        const int oc = m * 32 + (lane & 31);
        const int sl = (ks * 2 + (lane >> 5)) ^ (oc & 7);
        af[m][ks] = *(const bfx8*)((const char*)wbuf + oc * 128 + (sl << 4));
      }
#pragma unroll
    for (int ks = 0; ks < 4; ++ks) {
      bfx8 bf[2];
#pragma unroll
      for (int nn = 0; nn < 2; ++nn) {
        const int px = nn * 32 + (lane & 31) + dw;
        const int R = (wv + dh) * 66 + px;
        const int sl = (ks * 2 + (lane >> 5)) ^ (R & 7);
        bf[nn] = *(const bfx8*)((const char*)a_s + (size_t)R * 128 + (sl << 4));
      }
#pragma unroll
      for (int m = 0; m < 2; ++m)
#pragma unroll
        for (int nn = 0; nn < 2; ++nn)
          acc[m][nn] = __builtin_amdgcn_mfma_f32_32x32x16_bf16(
              af[m][ks], bf[nn], acc[m][nn], 0, 0, 0);
    }
    if (tap < 8) {
      uint4* wdst = (uint4*)w_s[(tap + 1) & 1];
      wdst[t] = wn0; wdst[t + 256] = wn1;
    }
    __syncthreads();
  }

  // ---- store C: D rows = oc (4 contiguous per reg-quad), cols = px
  const size_t obase = (((size_t)n * 258 + (h0 + wv + 1)) * 258 + (w0 + 1)) * 64;
#pragma unroll
  for (int m = 0; m < 2; ++m)
#pragma unroll
    for (int nn = 0; nn < 2; ++nn) {
      const int px = nn * 32 + (lane & 31);
#pragma unroll
      for (int q = 0; q < 4; ++q) {
        const int ocb = m * 32 + q * 8 + 4 * (lane >> 5);
        ushort4 o;
        o.x = f2bf(acc[m][nn][q * 4 + 0]);
        o.y = f2bf(acc[m][nn][q * 4 + 1]);
        o.z = f2bf(acc[m][nn][q * 4 + 2]);
        o.w = f2bf(acc[m][nn][q * 4 + 3]);
        *(ushort4*)(out + obase + (size_t)px * 64 + ocb) = o;
      }
    }

  // ---- fused BN partial stats (sum & sumsq over this block's 256 px)
  float sv[2][16], qv[2][16];
#pragma unroll
  for (int m = 0; m < 2; ++m)
#pragma unroll
    for (int r = 0; r < 16; ++r) {
      const float a0 = acc[m][0][r], a1 = acc[m][1][r];
      sv[m][r] = a0 + a1;
      qv[m][r] = a0 * a0 + a1 * a1;
    }
#pragma unroll
  for (int st = 1; st <= 16; st <<= 1)
#pragma unroll
    for (int m = 0; m < 2; ++m)
#pragma unroll
      for (int r = 0; r < 16; ++r) {
        sv[m][r] += __shfl_xor(sv[m][r], st);
        qv[m][r] += __shfl_xor(qv[m][r], st);
      }
#pragma unroll
  for (int r = 0; r < 16; ++r)
    if ((lane & 31) == r) {
#pragma unroll
      for (int m = 0; m < 2; ++m) {
        const int oc = m * 32 + (r & 3) + 8 * (r >> 2) + 4 * (lane >> 5);
        s_red[0][wv][oc] = sv[m][r];
        s_red[1][wv][oc] = qv[m][r];
      }
    }
  __syncthreads();
  if (t < 64) {
    psum[(size_t)t * NPB + b] = s_red[0][0][t] + s_red[0][1][t] + s_red[0][2][t] + s_red[0][3][t];
    psq[(size_t)t * NPB + b]  = s_red[1][0][t] + s_red[1][1][t] + s_red[1][2][t] + s_red[1][3][t];
  }
}

// ---- BN stats finalize: one block per channel, coalesced partial reduce
__global__ __launch_bounds__(256)
void k_bnfin(const float* __restrict__ psum, const float* __restrict__ psq,
             const float* __restrict__ g, const float* __restrict__ be,
             float* __restrict__ bnp, int nb) {
  __shared__ float s1[256], s2[256];
  const int c = blockIdx.x;  // 64 blocks
  const int t = threadIdx.x;
  float s = 0.f, q = 0.f;
  for (int j = t; j < nb; j += 256) {
    s += psum[(size_t)c * NPB + j];
    q += psq[(size_t)c * NPB + j];
  }
  s1[t] = s; s2[t] = q;
  __syncthreads();
  for (int st = 128; st > 0; st >>= 1) {
    if (t < st) { s1[t] += s1[t + st]; s2[t] += s2[t + st]; }
    __syncthreads();
  }
  if (t == 0) {
    const float m = s1[0] / PTOTF;
    const float var = s2[0] / PTOTF - m * m;
    const float sc = g[c] * rsqrtf(var + 1e-5f);
    bnp[c] = sc;
    bnp[64 + c] = be[c] - m * sc;
  }
}

// ---- elementwise on padded buffers: a = celu(y*sc+sh) + a   (residual)
__global__ __launch_bounds__(256)
void k_apply(const unsigned short* __restrict__ y, const float* __restrict__ bnp,
             unsigned short* __restrict__ a) {
  const size_t gid = (size_t)blockIdx.x * 256 + threadIdx.x;
  const int px = (int)(gid >> 3);
  const int c0 = ((int)gid & 7) * 8;
  const int n = px >> 16, hh = (px >> 8) & 255, ww = px & 255;
  const size_t i = padpx(n, hh, ww) * 64 + c0;
  float v[8];
  unpack8(*(const uint4*)(y + i), v);
  const float4 sa = *(const float4*)(bnp + c0);
  const float4 sb = *(const float4*)(bnp + c0 + 4);
  const float4 ha = *(const float4*)(bnp + 64 + c0);
  const float4 hb = *(const float4*)(bnp + 64 + c0 + 4);
  const float sc[8] = {sa.x, sa.y, sa.z, sa.w, sb.x, sb.y, sb.z, sb.w};
  const float sh[8] = {ha.x, ha.y, ha.z, ha.w, hb.x, hb.y, hb.z, hb.w};
  float r[8];
#pragma unroll
  for (int q = 0; q < 8; ++q) r[q] = celuf(v[q] * sc[q] + sh[q]);
  float av[8];
  unpack8(*(const uint4*)(a + i), av);
#pragma unroll
  for (int q = 0; q < 8; ++q) r[q] += av[q];
  uint4 o;
  o.x = (unsigned)f2bf(r[0]) | ((unsigned)f2bf(r[1]) << 16);
  o.y = (unsigned)f2bf(r[2]) | ((unsigned)f2bf(r[3]) << 16);
  o.z = (unsigned)f2bf(r[4]) | ((unsigned)f2bf(r[5]) << 16);
  o.w = (unsigned)f2bf(r[6]) | ((unsigned)f2bf(r[7]) << 16);
  *(uint4*)(a + i) = o;
}

// ---- RB1 residual: a = celu(bn2(y)) + celu(bn1(yb)); y may alias a (in-place)
__global__ __launch_bounds__(256)
void k_apply2(const unsigned short* y, const float* __restrict__ bnp2,
              const unsigned short* __restrict__ yb, const float* __restrict__ bnp1,
              unsigned short* a) {
  const size_t gid = (size_t)blockIdx.x * 256 + threadIdx.x;
  const int px = (int)(gid >> 3);
  const int c0 = ((int)gid & 7) * 8;
  const int n = px >> 16, hh = (px >> 8) & 255, ww = px & 255;
  const size_t i = padpx(n, hh, ww) * 64 + c0;
  float v[8], vb[8];
  unpack8(*(const uint4*)(y + i), v);
  unpack8(*(const uint4*)(yb + i), vb);
  float r[8];
#pragma unroll
  for (int q = 0; q < 8; ++q) {
    const int c = c0 + q;
    const float r2 = celuf(v[q] * bnp2[c] + bnp2[64 + c]);
    const float r1 = celuf(vb[q] * bnp1[c] + bnp1[64 + c]);
    r[q] = r1 + r2;
  }
  uint4 o;
  o.x = (unsigned)f2bf(r[0]) | ((unsigned)f2bf(r[1]) << 16);
  o.y = (unsigned)f2bf(r[2]) | ((unsigned)f2bf(r[3]) << 16);
  o.z = (unsigned)f2bf(r[4]) | ((unsigned)f2bf(r[5]) << 16);
  o.w = (unsigned)f2bf(r[6]) | ((unsigned)f2bf(r[7]) << 16);
  *(uint4*)(a + i) = o;
}

// ---- last conv 64->3 + bias + celu + x. LDS-tiled, low-VGPR.
__global__ __launch_bounds__(192)
void k_last(const unsigned short* __restrict__ a, const float* __restrict__ x,
            const float* __restrict__ wl, const float* __restrict__ b2,
            float* __restrict__ outp) {
  __shared__ __align__(16) unsigned short in_s[198 * 64];  // swizzled, 25344 B
  __shared__ float wsm[3][576];                             // [oc][tap*64+ic]

  const int t = threadIdx.x;
  const int b = blockIdx.x;
  const int n = b >> 10;
  const int h = (b >> 2) & 255;
  const int w0 = (b & 3) << 6;

  for (int j = t; j < 1728; j += 192) {
    const int oc = j / 576, k = j - oc * 576;
    const int tap = k >> 6, ic = k & 63;
    wsm[oc][k] = wl[tap * 256 + ic * 4 + oc];
  }
  for (int j = t; j < 1584; j += 192) {  // 198 rows x 8 chunks
    const int r = j >> 3, sl = j & 7;
    const int dh = r / 66, px = r - dh * 66;
    const uint4 u = *(const uint4*)(a +
        (((size_t)n * 258 + (h + dh)) * 258 + (w0 + px)) * 64 + sl * 8);
    *(uint4*)((char*)in_s + (size_t)r * 128 + ((sl ^ (r & 7)) << 4)) = u;
  }
  __syncthreads();

  const int px = t & 63;
  const int oc = t >> 6;  // 0..2
  float acc = 0.f;
#pragma unroll 1
  for (int tap = 0; tap < 9; ++tap) {
    const int dh = tap / 3, dw = tap - dh * 3;
    const int R = dh * 66 + px + dw;
    const float* wrow = &wsm[oc][tap * 64];
#pragma unroll
    for (int sl = 0; sl < 8; ++sl) {
      const uint4 u = *(const uint4*)((const char*)in_s +
          (size_t)R * 128 + ((sl ^ (R & 7)) << 4));
      float v[8];
      unpack8(u, v);
      const float4 wa = *(const float4*)(wrow + sl * 8);
      const float4 wb = *(const float4*)(wrow + sl * 8 + 4);
      acc += v[0] * wa.x + v[1] * wa.y + v[2] * wa.z + v[3] * wa.w +
             v[4] * wb.x + v[5] * wb.y + v[6] * wb.z + v[7] * wb.w;
    }
  }
  const size_t ob = (size_t)n * 3 * HW + (size_t)oc * HW + ((size_t)h << 8) + w0 + px;
  outp[ob] = celuf(acc + b2[oc]) + x[ob];
}

extern "C" void kernel_launch(void* const* d_in, const int* in_sizes, int n_in,
                              void* d_out, int out_size, void* d_ws, size_t ws_size,
                              hipStream_t stream) {
  const float* x   = (const float*)d_in[0];
  const float* w1  = (const float*)d_in[1];
  // d_in[2] = b1 (cancels under BN)
  const float* g1  = (const float*)d_in[3];
  const float* be1 = (const float*)d_in[4];
  const float* bw  = (const float*)d_in[5];
  // d_in[6] = bb (cancels under BN)
  const float* bg  = (const float*)d_in[7];
  const float* bbe = (const float*)d_in[8];
  const float* w2  = (const float*)d_in[9];
  const float* b2  = (const float*)d_in[10];
  float* out = (float*)d_out;

  const size_t PADBUF = (size_t)8 * 258 * 258 * 64 * 2;  // bytes
  size_t off = 0;
  auto alloc = [&](size_t bytes) {
    size_t cur = off;
    off += (bytes + 255) & ~(size_t)255;
    return cur;
  };
  const size_t oA   = alloc(PADBUF);
  const size_t oB   = alloc(PADBUF);
  const size_t oC   = alloc(PADBUF);
  const size_t oW1  = alloc(4608 * 4);
  const size_t oWM  = alloc((size_t)6 * 36864 * 2);  // bf16 swizzled
  const size_t oWL  = alloc(2304 * 4);
  const size_t oMS  = alloc(48 * 4);
  const size_t oBNP = alloc(7 * 128 * 4);
  const size_t oPS  = alloc((size_t)64 * NPB * 4);   // partial sums [ch][blk]
  const size_t oPQ  = alloc((size_t)64 * NPB * 4);   // partial sumsq
  if (off > ws_size) return;

  char* wsb = (char*)d_ws;
  unsigned short* bufA = (unsigned short*)(wsb + oA);
  unsigned short* bufB = (unsigned short*)(wsb + oB);
  unsigned short* bufC = (unsigned short*)(wsb + oC);
  float* wt1 = (float*)(wsb + oW1);
  unsigned short* wtm = (unsigned short*)(wsb + oWM);
  float* wtl = (float*)(wsb + oWL);
  float* ms  = (float*)(wsb + oMS);
  float* bnp = (float*)(wsb + oBNP);
  float* psum = (float*)(wsb + oPS);
  float* psq  = (float*)(wsb + oPQ);

  k_padzero<<<97, 256, 0, stream>>>(bufA, bufB, bufC);
  k_wt<<<8, 256, 0, stream>>>(w1, wt1, 64, 6, 8, 64);
  k_wtm<<<864, 256, 0, stream>>>(bw, wtm);
  k_wt<<<8, 256, 0, stream>>>(w2, wtl, 3, 64, 64, 4);
  k_inorm<<<24, 256, 0, stream>>>(x, ms);

  // conv1 (6->64) -> raw bufB (padded) + fused stats
  k_conv1<<<8192, 256, 0, stream>>>(x, ms, wt1, bufB, psum, psq);
  k_bnfin<<<64, 256, 0, stream>>>(psum, psq, g1, be1, bnp, 8192);  // bnp0

  // ResBlock 1 (input activation never materialized: MODE 2 from raw bufB)
  k_mconv<2><<<2048, 256, 0, stream>>>(bufB, bnp, wtm, bufC, psum, psq);
  k_bnfin<<<64, 256, 0, stream>>>(psum, psq, bg, bbe, bnp + 128, 2048);  // bnp1
  k_mconv<2><<<2048, 256, 0, stream>>>(bufC, bnp + 128, wtm + 36864, bufA, psum, psq);
  k_bnfin<<<64, 256, 0, stream>>>(psum, psq, bg + 64, bbe + 64, bnp + 256, 2048);  // bnp2
  // bufA = celu(bn2(bufA_raw)) + celu(bn0(bufB_raw))   (in-place)
  k_apply2<<<16384, 256, 0, stream>>>(bufA, bnp + 256, bufB, bnp, bufA);

  // ResBlocks 2,3
  for (int i = 1; i < 3; ++i) {
    const int s1 = 1 + 2 * i, s2 = 2 + 2 * i;
    k_mconv<1><<<2048, 256, 0, stream>>>(bufA, nullptr,
        wtm + (size_t)(2 * i) * 36864, bufB, psum, psq);
    k_bnfin<<<64, 256, 0, stream>>>(psum, psq, bg + (size_t)(2 * i) * 64,
        bbe + (size_t)(2 * i) * 64, bnp + (size_t)s1 * 128, 2048);
    k_mconv<2><<<2048, 256, 0, stream>>>(bufB, bnp + (size_t)s1 * 128,
        wtm + (size_t)(2 * i + 1) * 36864, bufC, psum, psq);
    k_bnfin<<<64, 256, 0, stream>>>(psum, psq, bg + (size_t)(2 * i + 1) * 64,
        bbe + (size_t)(2 * i + 1) * 64, bnp + (size_t)s2 * 128, 2048);
    k_apply<<<16384, 256, 0, stream>>>(bufC, bnp + (size_t)s2 * 128, bufA);
  }

  k_last<<<8192, 192, 0, stream>>>(bufA, x, wtl, b2, out);
}

// Round 9
// 967.574 us; speedup vs baseline: 6.6406x; 1.1518x over previous
//
#include <hip/hip_runtime.h>
#include <cstdint>
#include <cstddef>

#define DEVI __device__ __forceinline__

static constexpr int HW = 65536;          // 256*256
static constexpr float PTOTF = 524288.0f; // 8*256*256
static constexpr int NPB = 8192;          // partial-stats stride (max blocks)

typedef __attribute__((ext_vector_type(8))) short bfx8;
typedef __attribute__((ext_vector_type(16))) float fx16;

DEVI unsigned short f2bf(float f) {
  unsigned int x = __float_as_uint(f);
  x += 0x7fffu + ((x >> 16) & 1u);
  return (unsigned short)(x >> 16);
}
DEVI float celuf(float v) { return v > 0.0f ? v : expm1f(v); }

DEVI void unpack8(const uint4 u, float* v) {
  v[0] = __uint_as_float(u.x << 16); v[1] = __uint_as_float(u.x & 0xffff0000u);
  v[2] = __uint_as_float(u.y << 16); v[3] = __uint_as_float(u.y & 0xffff0000u);
  v[4] = __uint_as_float(u.z << 16); v[5] = __uint_as_float(u.z & 0xffff0000u);
  v[6] = __uint_as_float(u.w << 16); v[7] = __uint_as_float(u.w & 0xffff0000u);
}

// async 16B global->LDS (linear LDS dest = uniform base + lane*16)
DEVI void gload16(const unsigned short* g, unsigned short* l) {
  __builtin_amdgcn_global_load_lds(
      (const __attribute__((address_space(1))) unsigned int*)g,
      (__attribute__((address_space(3))) unsigned int*)l, 16, 0, 0);
}

// padded pixel base index: interior (n,h,w) -> element offset/64
DEVI size_t padpx(int n, int h, int w) {
  return ((size_t)n * 258 + (h + 1)) * 258 + (w + 1);
}

// ---- weight transform: src [OC][IC][3][3] -> dst [9][ICP][OCP] fp32 (conv1/last)
__global__ void k_wt(const float* __restrict__ w, float* __restrict__ dst,
                     int OC, int IC, int ICP, int OCP) {
  const int tot = 9 * ICP * OCP;
  for (int idx = blockIdx.x * blockDim.x + threadIdx.x; idx < tot;
       idx += gridDim.x * blockDim.x) {
    const int tap = idx / (ICP * OCP);
    const int r = idx - tap * (ICP * OCP);
    const int ic = r / OCP, oc = r - ic * OCP;
    dst[idx] = (ic < IC && oc < OC) ? w[(oc * IC + ic) * 9 + tap] : 0.0f;
  }
}

// ---- main-weight transform: bw [6][64][64][3][3] fp32 -> [6][9][64][64] bf16
__global__ void k_wtm(const float* __restrict__ w, unsigned short* __restrict__ dst) {
  const int idx = blockIdx.x * 256 + threadIdx.x;
  if (idx >= 6 * 36864) return;
  const int cv = idx / 36864, r = idx - cv * 36864;
  const int tap = r >> 12, rr = r & 4095, oc = rr >> 6, ic = rr & 63;
  const float v = w[((size_t)cv * 4096 + oc * 64 + ic) * 9 + tap];
  dst[(size_t)cv * 36864 + tap * 4096 + oc * 64 + ic] = f2bf(v);
}

// ---- zero the 1-px pad border of the three padded NHWC buffers
__global__ void k_padzero(unsigned short* a, unsigned short* b, unsigned short* c) {
  const int id = blockIdx.x * 256 + threadIdx.x;
  if (id >= 3 * 8 * 1028) return;
  const int buf = id / (8 * 1028), r = id - buf * (8 * 1028);
  const int n = r / 1028, k = r - n * 1028;
  int hp, wp;
  if (k < 258)      { hp = 0;           wp = k; }
  else if (k < 516) { hp = 257;         wp = k - 258; }
  else if (k < 772) { hp = k - 516 + 1; wp = 0; }
  else              { hp = k - 772 + 1; wp = 257; }
  unsigned short* p = (buf == 0 ? a : buf == 1 ? b : c) +
                      (((size_t)n * 258 + hp) * 258 + wp) * 64;
  const uint4 z = {0, 0, 0, 0};
#pragma unroll
  for (int q = 0; q < 8; ++q) ((uint4*)p)[q] = z;
}

// ---- instance norm stats: one block per (n,c)
__global__ __launch_bounds__(256)
void k_inorm(const float* __restrict__ x, float* __restrict__ ms) {
  __shared__ float s1[256], s2[256];
  const int b = blockIdx.x;
  const float4* p = (const float4*)(x + (size_t)b * HW);
  float sum = 0.f, sq = 0.f;
  for (int j = threadIdx.x; j < HW / 4; j += 256) {
    const float4 v = p[j];
    sum += v.x + v.y + v.z + v.w;
    sq  += v.x * v.x + v.y * v.y + v.z * v.z + v.w * v.w;
  }
  s1[threadIdx.x] = sum; s2[threadIdx.x] = sq;
  __syncthreads();
  for (int s = 128; s > 0; s >>= 1) {
    if ((int)threadIdx.x < s) {
      s1[threadIdx.x] += s1[threadIdx.x + s];
      s2[threadIdx.x] += s2[threadIdx.x + s];
    }
    __syncthreads();
  }
  if (threadIdx.x == 0) {
    const float m = s1[0] * (1.0f / HW);
    const float var = (s2[0] - s1[0] * s1[0] * (1.0f / HW)) * (1.0f / (HW - 1));
    ms[2 * b] = m;
    ms[2 * b + 1] = rsqrtf(var);
  }
}

// ---- conv1 (6->64), VALU path, padded raw bf16 out + fused BN partial stats
__global__ __launch_bounds__(256)
void k_conv1(const float* __restrict__ x, const float* __restrict__ ms,
             const float* __restrict__ wt, unsigned short* __restrict__ out,
             float* __restrict__ psum, float* __restrict__ psq) {
  __shared__ float in_s[3 * 66 * 9];
  __shared__ float w_s[9 * 8 * 64];
  __shared__ float red0[16][64], red1[16][64];

  const int t = threadIdx.x;
  const int b = blockIdx.x;
  const int n = b >> 10;
  const int h = (b >> 2) & 255;
  const int w0 = (b & 3) << 6;

  const float m0 = ms[6 * n + 0], r0 = ms[6 * n + 1];
  const float m1 = ms[6 * n + 2], r1 = ms[6 * n + 3];
  const float m2 = ms[6 * n + 4], r2 = ms[6 * n + 5];

  const int oc0 = (t & 15) * 4;
  const int px0 = (t >> 4) * 4;
  float acc[4][4] = {{0.f}};

  {
    const float4* wsrc = (const float4*)wt;
    for (int j4 = t; j4 < 1152; j4 += 256) ((float4*)w_s)[j4] = wsrc[j4];
  }
  if (t < 198) {
    const int dh = t / 66, px = t - dh * 66;
    const int gh = h + dh - 1, gw = w0 + px - 1;
    const bool ok = ((unsigned)gh < 256u) && ((unsigned)gw < 256u);
    float v[8];
    if (ok) {
      const float* xp = x + (size_t)n * 3 * HW + gh * 256 + gw;
      const float a0 = xp[0], a1 = xp[HW], a2 = xp[2 * HW];
      v[0] = a0; v[1] = a1; v[2] = a2;
      v[3] = (a0 - m0) * r0; v[4] = (a1 - m1) * r1; v[5] = (a2 - m2) * r2;
      v[6] = 0.f; v[7] = 0.f;
    } else {
#pragma unroll
      for (int q = 0; q < 8; ++q) v[q] = 0.f;
    }
    float* d = &in_s[(dh * 66 + px) * 9];
#pragma unroll
    for (int q = 0; q < 8; ++q) d[q] = v[q];
  }
  __syncthreads();
#pragma unroll
  for (int i = 0; i < 8; ++i) {
    float xv[3][6];
#pragma unroll
    for (int dh = 0; dh < 3; ++dh)
#pragma unroll
      for (int j = 0; j < 6; ++j)
        xv[dh][j] = in_s[(dh * 66 + px0 + j) * 9 + i];
#pragma unroll
    for (int dh = 0; dh < 3; ++dh)
#pragma unroll
      for (int dw = 0; dw < 3; ++dw) {
        const float4 wv = *(const float4*)&w_s[((dh * 3 + dw) * 8 + i) * 64 + oc0];
#pragma unroll
        for (int p = 0; p < 4; ++p) {
          const float xin = xv[dh][p + dw];
          acc[p][0] += xin * wv.x;
          acc[p][1] += xin * wv.y;
          acc[p][2] += xin * wv.z;
          acc[p][3] += xin * wv.w;
        }
      }
  }
  unsigned short* ob = out + (((size_t)n * 258 + (h + 1)) * 258 + (w0 + 1)) * 64;
#pragma unroll
  for (int p = 0; p < 4; ++p) {
    ushort4 o;
    o.x = f2bf(acc[p][0]); o.y = f2bf(acc[p][1]);
    o.z = f2bf(acc[p][2]); o.w = f2bf(acc[p][3]);
    *(ushort4*)(ob + (size_t)(px0 + p) * 64 + oc0) = o;
  }
#pragma unroll
  for (int q = 0; q < 4; ++q) {
    float s = 0.f, qv = 0.f;
#pragma unroll
    for (int p = 0; p < 4; ++p) { s += acc[p][q]; qv += acc[p][q] * acc[p][q]; }
    red0[t >> 4][oc0 + q] = s;
    red1[t >> 4][oc0 + q] = qv;
  }
  __syncthreads();
  if (t < 64) {
    float s = 0.f, qv = 0.f;
#pragma unroll
    for (int g2 = 0; g2 < 16; ++g2) { s += red0[g2][t]; qv += red1[g2][t]; }
    psum[(size_t)t * NPB + b] = s;
    psq[(size_t)t * NPB + b]  = qv;
  }
}

// ---- MFMA implicit-GEMM 3x3 conv 64->64, padded bf16 NHWC act in / raw out.
// Staging: global_load_lds w16 with pre-swizzled global source (linear LDS).
// Weights: per-tap direct global reads (L1/L2 broadcast), register prefetch.
// Block: 4 rows x 64 px x 64 oc, 4 waves; 1 barrier before taps, none inside.
// Fused BN partial stats via 1 shfl fold + LDS transpose-reduce (a_s reuse).
__global__ __launch_bounds__(256, 3)
void k_mconv(const unsigned short* __restrict__ in,
             const unsigned short* __restrict__ wt,
             unsigned short* __restrict__ out,
             float* __restrict__ psum, float* __restrict__ psq) {
  __shared__ __align__(16) unsigned short a_s[3168 * 8];  // 50688 B
  __shared__ float s_finS[4][64], s_finQ[4][64];

  const int t = threadIdx.x;
  const int lane = t & 63, wv = t >> 6;
  const int oc_l = lane & 31, hi = lane >> 5;
  int b = blockIdx.x;
  b = (b & 7) * 256 + (b >> 3);  // XCD swizzle (2048 = 8*256, bijective)
  const int n  = b >> 8;
  const int h0 = ((b >> 2) & 63) * 4;
  const int w0 = (b & 3) * 64;

  const size_t ibase = ((size_t)n * 258 + h0) * 258 + w0;

  // ---- async stage A tile [6 rows][66 px][64 ic]: 54 segs (6 rows x 9 parts)
  for (int seg = wv; seg < 54; seg += 4) {
    const int r = seg / 9;
    const int p = seg - r * 9;
    const int c = p * 64 + lane;          // chunk in row, row has 528
    const int px = c >> 3;
    const int R = r * 66 + px;
    const int sl = (c & 7) ^ (R & 7);     // pre-swizzled source slice
    const unsigned short* gsrc = in + (ibase + (size_t)r * 258 + px) * 64 + sl * 8;
    unsigned short* ldst = a_s + (size_t)(r * 528 + p * 64) * 8;  // uniform base
    if (c < 528) gload16(gsrc, ldst);
  }
  __syncthreads();  // drains vmcnt before barrier (compiler-inserted)

  // ---- weights tap 0 into regs
  bfx8 afc[2][4], afn[2][4];
#pragma unroll
  for (int m = 0; m < 2; ++m)
#pragma unroll
    for (int ks = 0; ks < 4; ++ks)
      afc[m][ks] = *(const bfx8*)(wt + (size_t)(m * 32 + oc_l) * 64 + (ks * 2 + hi) * 8);

  fx16 acc[2][2] = {};

#pragma unroll
  for (int tap = 0; tap < 9; ++tap) {
    const int dh = tap / 3, dw = tap - dh * 3;
    if (tap < 8) {  // prefetch next tap's weights (hidden under MFMA)
#pragma unroll
      for (int m = 0; m < 2; ++m)
#pragma unroll
        for (int ks = 0; ks < 4; ++ks)
          afn[m][ks] = *(const bfx8*)(wt + (size_t)(tap + 1) * 4096 +
                                      (size_t)(m * 32 + oc_l) * 64 + (ks * 2 + hi) * 8);
    }
#pragma unroll
    for (int ks = 0; ks < 4; ++ks) {
      bfx8 bf[2];
#pragma unroll
      for (int nn = 0; nn < 2; ++nn) {
        const int px = nn * 32 + oc_l + dw;
        const int R = (wv + dh) * 66 + px;
        const int sl = (ks * 2 + hi) ^ (R & 7);
        bf[nn] = *(const bfx8*)((const char*)a_s + (size_t)R * 128 + (sl << 4));
      }
#pragma unroll
      for (int m = 0; m < 2; ++m)
#pragma unroll
        for (int nn = 0; nn < 2; ++nn)
          acc[m][nn] = __builtin_amdgcn_mfma_f32_32x32x16_bf16(
              afc[m][ks], bf[nn], acc[m][nn], 0, 0, 0);
    }
    if (tap < 8) {
#pragma unroll
      for (int m = 0; m < 2; ++m)
#pragma unroll
        for (int ks = 0; ks < 4; ++ks)
          afc[m][ks] = afn[m][ks];
    }
  }

  // ---- store C: D rows = oc, cols = px
  const size_t obase = (((size_t)n * 258 + (h0 + wv + 1)) * 258 + (w0 + 1)) * 64;
#pragma unroll
  for (int m = 0; m < 2; ++m)
#pragma unroll
    for (int nn = 0; nn < 2; ++nn) {
      const int px = nn * 32 + oc_l;
#pragma unroll
      for (int q = 0; q < 4; ++q) {
        const int ocb = m * 32 + q * 8 + 4 * hi;
        ushort4 o;
        o.x = f2bf(acc[m][nn][q * 4 + 0]);
        o.y = f2bf(acc[m][nn][q * 4 + 1]);
        o.z = f2bf(acc[m][nn][q * 4 + 2]);
        o.w = f2bf(acc[m][nn][q * 4 + 3]);
        *(ushort4*)(out + obase + (size_t)px * 64 + ocb) = o;
      }
    }

  // ---- fused BN partial stats: lane-local + 1 shfl fold + LDS reduce
  float sv[2][16], qv[2][16];
#pragma unroll
  for (int m = 0; m < 2; ++m)
#pragma unroll
    for (int r = 0; r < 16; ++r) {
      const float a0 = acc[m][0][r], a1 = acc[m][1][r];
      sv[m][r] = a0 + a1;
      qv[m][r] = a0 * a0 + a1 * a1;
    }
#pragma unroll
  for (int m = 0; m < 2; ++m)
#pragma unroll
    for (int r = 0; r < 16; ++r) {
      sv[m][r] += __shfl_xor(sv[m][r], 16);
      qv[m][r] += __shfl_xor(qv[m][r], 16);
    }
  __syncthreads();  // all waves done reading a_s -> reuse as f32 scratch
  float* fS = (float*)a_s;            // [4][64][17]
  float* fQ = fS + 4 * 64 * 17;
  if ((lane & 31) < 16) {
    const int l16 = lane & 15;
#pragma unroll
    for (int m = 0; m < 2; ++m)
#pragma unroll
      for (int r = 0; r < 16; ++r) {
        const int oc = m * 32 + (r & 3) + 8 * (r >> 2) + 4 * hi;
        fS[(wv * 64 + oc) * 17 + l16] = sv[m][r];
        fQ[(wv * 64 + oc) * 17 + l16] = qv[m][r];
      }
  }
  __syncthreads();
  {
    const int oc = t & 63, sub = t >> 6;
    float s = 0.f, q = 0.f;
#pragma unroll
    for (int j = 0; j < 16; ++j) {
      s += fS[(sub * 64 + oc) * 17 + j];
      q += fQ[(sub * 64 + oc) * 17 + j];
    }
    s_finS[sub][oc] = s; s_finQ[sub][oc] = q;
  }
  __syncthreads();
  if (t < 64) {
    psum[(size_t)t * NPB + b] = s_finS[0][t] + s_finS[1][t] + s_finS[2][t] + s_finS[3][t];
    psq [(size_t)t * NPB + b] = s_finQ[0][t] + s_finQ[1][t] + s_finQ[2][t] + s_finQ[3][t];
  }
}

// ---- BN stats finalize: one block per channel, coalesced partial reduce
__global__ __launch_bounds__(256)
void k_bnfin(const float* __restrict__ psum, const float* __restrict__ psq,
             const float* __restrict__ g, const float* __restrict__ be,
             float* __restrict__ bnp, int nb) {
  __shared__ float s1[256], s2[256];
  const int c = blockIdx.x;
  const int t = threadIdx.x;
  float s = 0.f, q = 0.f;
  for (int j = t; j < nb; j += 256) {
    s += psum[(size_t)c * NPB + j];
    q += psq[(size_t)c * NPB + j];
  }
  s1[t] = s; s2[t] = q;
  __syncthreads();
  for (int st = 128; st > 0; st >>= 1) {
    if (t < st) { s1[t] += s1[t + st]; s2[t] += s2[t + st]; }
    __syncthreads();
  }
  if (t == 0) {
    const float m = s1[0] / PTOTF;
    const float var = s2[0] / PTOTF - m * m;
    const float sc = g[c] * rsqrtf(var + 1e-5f);
    bnp[c] = sc;
    bnp[64 + c] = be[c] - m * sc;
  }
}

// ---- elementwise: RES=0: a = celu(bn(y));  RES=1: a += celu(bn(y))
template<int RES>
__global__ __launch_bounds__(256)
void k_apply(const unsigned short* __restrict__ y, const float* __restrict__ bnp,
             unsigned short* __restrict__ a) {
  const size_t gid = (size_t)blockIdx.x * 256 + threadIdx.x;
  const int px = (int)(gid >> 3);
  const int c0 = ((int)gid & 7) * 8;
  const int n = px >> 16, hh = (px >> 8) & 255, ww = px & 255;
  const size_t i = padpx(n, hh, ww) * 64 + c0;
  float v[8];
  unpack8(*(const uint4*)(y + i), v);
  const float4 sa = *(const float4*)(bnp + c0);
  const float4 sb = *(const float4*)(bnp + c0 + 4);
  const float4 ha = *(const float4*)(bnp + 64 + c0);
  const float4 hb = *(const float4*)(bnp + 64 + c0 + 4);
  const float sc[8] = {sa.x, sa.y, sa.z, sa.w, sb.x, sb.y, sb.z, sb.w};
  const float sh[8] = {ha.x, ha.y, ha.z, ha.w, hb.x, hb.y, hb.z, hb.w};
  float r[8];
#pragma unroll
  for (int q = 0; q < 8; ++q) r[q] = celuf(v[q] * sc[q] + sh[q]);
  if (RES) {
    float av[8];
    unpack8(*(const uint4*)(a + i), av);
#pragma unroll
    for (int q = 0; q < 8; ++q) r[q] += av[q];
  }
  uint4 o;
  o.x = (unsigned)f2bf(r[0]) | ((unsigned)f2bf(r[1]) << 16);
  o.y = (unsigned)f2bf(r[2]) | ((unsigned)f2bf(r[3]) << 16);
  o.z = (unsigned)f2bf(r[4]) | ((unsigned)f2bf(r[5]) << 16);
  o.w = (unsigned)f2bf(r[6]) | ((unsigned)f2bf(r[7]) << 16);
  *(uint4*)(a + i) = o;
}

// ---- last conv 64->3 + bias + celu + x. LDS-tiled, low-VGPR.
__global__ __launch_bounds__(192)
void k_last(const unsigned short* __restrict__ a, const float* __restrict__ x,
            const float* __restrict__ wl, const float* __restrict__ b2,
            float* __restrict__ outp) {
  __shared__ __align__(16) unsigned short in_s[198 * 64];
  __shared__ float wsm[3][576];

  const int t = threadIdx.x;
  const int b = blockIdx.x;
  const int n = b >> 10;
  const int h = (b >> 2) & 255;
  const int w0 = (b & 3) << 6;

  for (int j = t; j < 1728; j += 192) {
    const int oc = j / 576, k = j - oc * 576;
    const int tap = k >> 6, ic = k & 63;
    wsm[oc][k] = wl[tap * 256 + ic * 4 + oc];
  }
  for (int j = t; j < 1584; j += 192) {
    const int r = j >> 3, sl = j & 7;
    const int dh = r / 66, px = r - dh * 66;
    const uint4 u = *(const uint4*)(a +
        (((size_t)n * 258 + (h + dh)) * 258 + (w0 + px)) * 64 + sl * 8);
    *(uint4*)((char*)in_s + (size_t)r * 128 + ((sl ^ (r & 7)) << 4)) = u;
  }
  __syncthreads();

  const int px = t & 63;
  const int oc = t >> 6;
  float acc = 0.f;
#pragma unroll 1
  for (int tap = 0; tap < 9; ++tap) {
    const int dh = tap / 3, dw = tap - dh * 3;
    const int R = dh * 66 + px + dw;
    const float* wrow = &wsm[oc][tap * 64];
#pragma unroll
    for (int sl = 0; sl < 8; ++sl) {
      const uint4 u = *(const uint4*)((const char*)in_s +
          (size_t)R * 128 + ((sl ^ (R & 7)) << 4));
      float v[8];
      unpack8(u, v);
      const float4 wa = *(const float4*)(wrow + sl * 8);
      const float4 wb = *(const float4*)(wrow + sl * 8 + 4);
      acc += v[0] * wa.x + v[1] * wa.y + v[2] * wa.z + v[3] * wa.w +
             v[4] * wb.x + v[5] * wb.y + v[6] * wb.z + v[7] * wb.w;
    }
  }
  const size_t ob = (size_t)n * 3 * HW + (size_t)oc * HW + ((size_t)h << 8) + w0 + px;
  outp[ob] = celuf(acc + b2[oc]) + x[ob];
}

extern "C" void kernel_launch(void* const* d_in, const int* in_sizes, int n_in,
                              void* d_out, int out_size, void* d_ws, size_t ws_size,
                              hipStream_t stream) {
  const float* x   = (const float*)d_in[0];
  const float* w1  = (const float*)d_in[1];
  // d_in[2] = b1 (cancels under BN)
  const float* g1  = (const float*)d_in[3];
  const float* be1 = (const float*)d_in[4];
  const float* bw  = (const float*)d_in[5];
  // d_in[6] = bb (cancels under BN)
  const float* bg  = (const float*)d_in[7];
  const float* bbe = (const float*)d_in[8];
  const float* w2  = (const float*)d_in[9];
  const float* b2  = (const float*)d_in[10];
  float* out = (float*)d_out;

  const size_t PADBUF = (size_t)8 * 258 * 258 * 64 * 2;  // bytes
  size_t off = 0;
  auto alloc = [&](size_t bytes) {
    size_t cur = off;
    off += (bytes + 255) & ~(size_t)255;
    return cur;
  };
  const size_t oA   = alloc(PADBUF);
  const size_t oB   = alloc(PADBUF);
  const size_t oC   = alloc(PADBUF);
  const size_t oW1  = alloc(4608 * 4);
  const size_t oWM  = alloc((size_t)6 * 36864 * 2);  // bf16 [cv][9][64][64]
  const size_t oWL  = alloc(2304 * 4);
  const size_t oMS  = alloc(48 * 4);
  const size_t oBNP = alloc(7 * 128 * 4);
  const size_t oPS  = alloc((size_t)64 * NPB * 4);
  const size_t oPQ  = alloc((size_t)64 * NPB * 4);
  if (off > ws_size) return;

  char* wsb = (char*)d_ws;
  unsigned short* bufA = (unsigned short*)(wsb + oA);
  unsigned short* bufB = (unsigned short*)(wsb + oB);
  unsigned short* bufC = (unsigned short*)(wsb + oC);
  float* wt1 = (float*)(wsb + oW1);
  unsigned short* wtm = (unsigned short*)(wsb + oWM);
  float* wtl = (float*)(wsb + oWL);
  float* ms  = (float*)(wsb + oMS);
  float* bnp = (float*)(wsb + oBNP);
  float* psum = (float*)(wsb + oPS);
  float* psq  = (float*)(wsb + oPQ);

  k_padzero<<<97, 256, 0, stream>>>(bufA, bufB, bufC);
  k_wt<<<8, 256, 0, stream>>>(w1, wt1, 64, 6, 8, 64);
  k_wtm<<<864, 256, 0, stream>>>(bw, wtm);
  k_wt<<<8, 256, 0, stream>>>(w2, wtl, 3, 64, 64, 4);
  k_inorm<<<24, 256, 0, stream>>>(x, ms);

  // conv1 (6->64) -> raw bufB + fused stats; act0 -> bufA
  k_conv1<<<8192, 256, 0, stream>>>(x, ms, wt1, bufB, psum, psq);
  k_bnfin<<<64, 256, 0, stream>>>(psum, psq, g1, be1, bnp, 8192);
  k_apply<0><<<16384, 256, 0, stream>>>(bufB, bnp, bufA);

  for (int i = 0; i < 3; ++i) {
    const int s1 = 1 + 2 * i, s2 = 2 + 2 * i;
    // conv A (act) -> B raw
    k_mconv<<<2048, 256, 0, stream>>>(bufA, wtm + (size_t)(2 * i) * 36864,
                                      bufB, psum, psq);
    k_bnfin<<<64, 256, 0, stream>>>(psum, psq, bg + (size_t)(2 * i) * 64,
        bbe + (size_t)(2 * i) * 64, bnp + (size_t)s1 * 128, 2048);
    // act mid -> C
    k_apply<0><<<16384, 256, 0, stream>>>(bufB, bnp + (size_t)s1 * 128, bufC);
    // conv C (act) -> B raw
    k_mconv<<<2048, 256, 0, stream>>>(bufC, wtm + (size_t)(2 * i + 1) * 36864,
                                      bufB, psum, psq);
    k_bnfin<<<64, 256, 0, stream>>>(psum, psq, bg + (size_t)(2 * i + 1) * 64,
        bbe + (size_t)(2 * i + 1) * 64, bnp + (size_t)s2 * 128, 2048);
    // residual: A += celu(bn(B))
    k_apply<1><<<16384, 256, 0, stream>>>(bufB, bnp + (size_t)s2 * 128, bufA);
  }

  k_last<<<8192, 192, 0, stream>>>(bufA, x, wtl, b2, out);
}

// Round 10
// 923.190 us; speedup vs baseline: 6.9599x; 1.0481x over previous
//
#include <hip/hip_runtime.h>
#include <cstdint>
#include <cstddef>

#define DEVI __device__ __forceinline__

static constexpr int HW = 65536;          // 256*256
static constexpr float PTOTF = 524288.0f; // 8*256*256
static constexpr int NPB = 8192;          // partial-stats stride (max blocks)

typedef __attribute__((ext_vector_type(8))) short bfx8;
typedef __attribute__((ext_vector_type(16))) float fx16;

DEVI unsigned short f2bf(float f) {
  unsigned int x = __float_as_uint(f);
  x += 0x7fffu + ((x >> 16) & 1u);
  return (unsigned short)(x >> 16);
}
DEVI float celuf(float v) { return v > 0.0f ? v : expm1f(v); }

DEVI void unpack8(const uint4 u, float* v) {
  v[0] = __uint_as_float(u.x << 16); v[1] = __uint_as_float(u.x & 0xffff0000u);
  v[2] = __uint_as_float(u.y << 16); v[3] = __uint_as_float(u.y & 0xffff0000u);
  v[4] = __uint_as_float(u.z << 16); v[5] = __uint_as_float(u.z & 0xffff0000u);
  v[6] = __uint_as_float(u.w << 16); v[7] = __uint_as_float(u.w & 0xffff0000u);
}

// async 16B global->LDS (linear LDS dest = uniform base + lane*16)
DEVI void gload16(const unsigned short* g, unsigned short* l) {
  __builtin_amdgcn_global_load_lds(
      (const __attribute__((address_space(1))) unsigned int*)g,
      (__attribute__((address_space(3))) unsigned int*)l, 16, 0, 0);
}

// padded pixel base index: interior (n,h,w) -> element offset/64
DEVI size_t padpx(int n, int h, int w) {
  return ((size_t)n * 258 + (h + 1)) * 258 + (w + 1);
}

// ---- merged prep: pad-zero borders + all three weight transforms
__global__ __launch_bounds__(256)
void k_prep(const float* __restrict__ w1, const float* __restrict__ bw,
            const float* __restrict__ w2, float* __restrict__ wt1,
            unsigned short* __restrict__ wtm, float* __restrict__ wtl,
            unsigned short* a, unsigned short* b, unsigned short* c) {
  int id = blockIdx.x * 256 + threadIdx.x;
  if (id < 24672) {  // pad-zero: 3 bufs x 8 n x 1028 border px
    const int buf = id / 8224, r = id - buf * 8224;
    const int n = r / 1028, k = r - n * 1028;
    int hp, wp;
    if (k < 258)      { hp = 0;           wp = k; }
    else if (k < 516) { hp = 257;         wp = k - 258; }
    else if (k < 772) { hp = k - 516 + 1; wp = 0; }
    else              { hp = k - 772 + 1; wp = 257; }
    unsigned short* p = (buf == 0 ? a : buf == 1 ? b : c) +
                        (((size_t)n * 258 + hp) * 258 + wp) * 64;
    const uint4 z = {0, 0, 0, 0};
#pragma unroll
    for (int q = 0; q < 8; ++q) ((uint4*)p)[q] = z;
    return;
  }
  id -= 24672;
  if (id < 221184) {  // wtm: bw [6][64][64][3][3] f32 -> [6][9][64][64] bf16
    const int cv = id / 36864, r = id - cv * 36864;
    const int tap = r >> 12, rr = r & 4095, oc = rr >> 6, ic = rr & 63;
    const float v = bw[((size_t)cv * 4096 + oc * 64 + ic) * 9 + tap];
    wtm[(size_t)cv * 36864 + tap * 4096 + oc * 64 + ic] = f2bf(v);
    return;
  }
  id -= 221184;
  if (id < 4608) {  // wt1: [9][8][64], src [64][6][3][3]
    const int tap = id / 512, rr = id - tap * 512, ic = rr >> 6, oc = rr & 63;
    wt1[id] = (ic < 6) ? w1[(oc * 6 + ic) * 9 + tap] : 0.0f;
    return;
  }
  id -= 4608;
  if (id < 2304) {  // wtl: [9][64][4], src [3][64][3][3]
    const int tap = id / 256, rr = id - tap * 256, ic = rr >> 2, oc = rr & 3;
    wtl[id] = (oc < 3) ? w2[(oc * 64 + ic) * 9 + tap] : 0.0f;
  }
}

// ---- instance norm stats: one block per (n,c)
__global__ __launch_bounds__(256)
void k_inorm(const float* __restrict__ x, float* __restrict__ ms) {
  __shared__ float s1[256], s2[256];
  const int b = blockIdx.x;
  const float4* p = (const float4*)(x + (size_t)b * HW);
  float sum = 0.f, sq = 0.f;
  for (int j = threadIdx.x; j < HW / 4; j += 256) {
    const float4 v = p[j];
    sum += v.x + v.y + v.z + v.w;
    sq  += v.x * v.x + v.y * v.y + v.z * v.z + v.w * v.w;
  }
  s1[threadIdx.x] = sum; s2[threadIdx.x] = sq;
  __syncthreads();
  for (int s = 128; s > 0; s >>= 1) {
    if ((int)threadIdx.x < s) {
      s1[threadIdx.x] += s1[threadIdx.x + s];
      s2[threadIdx.x] += s2[threadIdx.x + s];
    }
    __syncthreads();
  }
  if (threadIdx.x == 0) {
    const float m = s1[0] * (1.0f / HW);
    const float var = (s2[0] - s1[0] * s1[0] * (1.0f / HW)) * (1.0f / (HW - 1));
    ms[2 * b] = m;
    ms[2 * b + 1] = rsqrtf(var);
  }
}

// ---- conv1 (6->64), VALU path, padded raw bf16 out + fused BN partial stats
__global__ __launch_bounds__(256)
void k_conv1(const float* __restrict__ x, const float* __restrict__ ms,
             const float* __restrict__ wt, unsigned short* __restrict__ out,
             float* __restrict__ psum, float* __restrict__ psq) {
  __shared__ float in_s[3 * 66 * 9];
  __shared__ float w_s[9 * 8 * 64];
  __shared__ float red0[16][64], red1[16][64];

  const int t = threadIdx.x;
  const int b = blockIdx.x;
  const int n = b >> 10;
  const int h = (b >> 2) & 255;
  const int w0 = (b & 3) << 6;

  const float m0 = ms[6 * n + 0], r0 = ms[6 * n + 1];
  const float m1 = ms[6 * n + 2], r1 = ms[6 * n + 3];
  const float m2 = ms[6 * n + 4], r2 = ms[6 * n + 5];

  const int oc0 = (t & 15) * 4;
  const int px0 = (t >> 4) * 4;
  float acc[4][4] = {{0.f}};

  {
    const float4* wsrc = (const float4*)wt;
    for (int j4 = t; j4 < 1152; j4 += 256) ((float4*)w_s)[j4] = wsrc[j4];
  }
  if (t < 198) {
    const int dh = t / 66, px = t - dh * 66;
    const int gh = h + dh - 1, gw = w0 + px - 1;
    const bool ok = ((unsigned)gh < 256u) && ((unsigned)gw < 256u);
    float v[8];
    if (ok) {
      const float* xp = x + (size_t)n * 3 * HW + gh * 256 + gw;
      const float a0 = xp[0], a1 = xp[HW], a2 = xp[2 * HW];
      v[0] = a0; v[1] = a1; v[2] = a2;
      v[3] = (a0 - m0) * r0; v[4] = (a1 - m1) * r1; v[5] = (a2 - m2) * r2;
      v[6] = 0.f; v[7] = 0.f;
    } else {
#pragma unroll
      for (int q = 0; q < 8; ++q) v[q] = 0.f;
    }
    float* d = &in_s[(dh * 66 + px) * 9];
#pragma unroll
    for (int q = 0; q < 8; ++q) d[q] = v[q];
  }
  __syncthreads();
#pragma unroll
  for (int i = 0; i < 8; ++i) {
    float xv[3][6];
#pragma unroll
    for (int dh = 0; dh < 3; ++dh)
#pragma unroll
      for (int j = 0; j < 6; ++j)
        xv[dh][j] = in_s[(dh * 66 + px0 + j) * 9 + i];
#pragma unroll
    for (int dh = 0; dh < 3; ++dh)
#pragma unroll
      for (int dw = 0; dw < 3; ++dw) {
        const float4 wv = *(const float4*)&w_s[((dh * 3 + dw) * 8 + i) * 64 + oc0];
#pragma unroll
        for (int p = 0; p < 4; ++p) {
          const float xin = xv[dh][p + dw];
          acc[p][0] += xin * wv.x;
          acc[p][1] += xin * wv.y;
          acc[p][2] += xin * wv.z;
          acc[p][3] += xin * wv.w;
        }
      }
  }
  unsigned short* ob = out + (((size_t)n * 258 + (h + 1)) * 258 + (w0 + 1)) * 64;
#pragma unroll
  for (int p = 0; p < 4; ++p) {
    ushort4 o;
    o.x = f2bf(acc[p][0]); o.y = f2bf(acc[p][1]);
    o.z = f2bf(acc[p][2]); o.w = f2bf(acc[p][3]);
    *(ushort4*)(ob + (size_t)(px0 + p) * 64 + oc0) = o;
  }
#pragma unroll
  for (int q = 0; q < 4; ++q) {
    float s = 0.f, qv = 0.f;
#pragma unroll
    for (int p = 0; p < 4; ++p) { s += acc[p][q]; qv += acc[p][q] * acc[p][q]; }
    red0[t >> 4][oc0 + q] = s;
    red1[t >> 4][oc0 + q] = qv;
  }
  __syncthreads();
  if (t < 64) {
    float s = 0.f, qv = 0.f;
#pragma unroll
    for (int g2 = 0; g2 < 16; ++g2) { s += red0[g2][t]; qv += red1[g2][t]; }
    psum[(size_t)t * NPB + b] = s;
    psq[(size_t)t * NPB + b]  = qv;
  }
}

// ---- MFMA implicit-GEMM 3x3 conv 64->64, padded bf16 NHWC act in / raw out.
__global__ __launch_bounds__(256, 3)
void k_mconv(const unsigned short* __restrict__ in,
             const unsigned short* __restrict__ wt,
             unsigned short* __restrict__ out,
             float* __restrict__ psum, float* __restrict__ psq) {
  __shared__ __align__(16) unsigned short a_s[3168 * 8];  // 50688 B
  __shared__ float s_finS[4][64], s_finQ[4][64];

  const int t = threadIdx.x;
  const int lane = t & 63, wv = t >> 6;
  const int oc_l = lane & 31, hi = lane >> 5;
  int b = blockIdx.x;
  b = (b & 7) * 256 + (b >> 3);  // XCD swizzle (2048 = 8*256, bijective)
  const int n  = b >> 8;
  const int h0 = ((b >> 2) & 63) * 4;
  const int w0 = (b & 3) * 64;

  const size_t ibase = ((size_t)n * 258 + h0) * 258 + w0;

  for (int seg = wv; seg < 54; seg += 4) {
    const int r = seg / 9;
    const int p = seg - r * 9;
    const int c = p * 64 + lane;
    const int px = c >> 3;
    const int R = r * 66 + px;
    const int sl = (c & 7) ^ (R & 7);
    const unsigned short* gsrc = in + (ibase + (size_t)r * 258 + px) * 64 + sl * 8;
    unsigned short* ldst = a_s + (size_t)(r * 528 + p * 64) * 8;
    if (c < 528) gload16(gsrc, ldst);
  }
  __syncthreads();

  bfx8 afc[2][4], afn[2][4];
#pragma unroll
  for (int m = 0; m < 2; ++m)
#pragma unroll
    for (int ks = 0; ks < 4; ++ks)
      afc[m][ks] = *(const bfx8*)(wt + (size_t)(m * 32 + oc_l) * 64 + (ks * 2 + hi) * 8);

  fx16 acc[2][2] = {};

#pragma unroll
  for (int tap = 0; tap < 9; ++tap) {
    const int dh = tap / 3, dw = tap - dh * 3;
    if (tap < 8) {
#pragma unroll
      for (int m = 0; m < 2; ++m)
#pragma unroll
        for (int ks = 0; ks < 4; ++ks)
          afn[m][ks] = *(const bfx8*)(wt + (size_t)(tap + 1) * 4096 +
                                      (size_t)(m * 32 + oc_l) * 64 + (ks * 2 + hi) * 8);
    }
#pragma unroll
    for (int ks = 0; ks < 4; ++ks) {
      bfx8 bf[2];
#pragma unroll
      for (int nn = 0; nn < 2; ++nn) {
        const int px = nn * 32 + oc_l + dw;
        const int R = (wv + dh) * 66 + px;
        const int sl = (ks * 2 + hi) ^ (R & 7);
        bf[nn] = *(const bfx8*)((const char*)a_s + (size_t)R * 128 + (sl << 4));
      }
#pragma unroll
      for (int m = 0; m < 2; ++m)
#pragma unroll
        for (int nn = 0; nn < 2; ++nn)
          acc[m][nn] = __builtin_amdgcn_mfma_f32_32x32x16_bf16(
              afc[m][ks], bf[nn], acc[m][nn], 0, 0, 0);
    }
    if (tap < 8) {
#pragma unroll
      for (int m = 0; m < 2; ++m)
#pragma unroll
        for (int ks = 0; ks < 4; ++ks)
          afc[m][ks] = afn[m][ks];
    }
  }

  const size_t obase = (((size_t)n * 258 + (h0 + wv + 1)) * 258 + (w0 + 1)) * 64;
#pragma unroll
  for (int m = 0; m < 2; ++m)
#pragma unroll
    for (int nn = 0; nn < 2; ++nn) {
      const int px = nn * 32 + oc_l;
#pragma unroll
      for (int q = 0; q < 4; ++q) {
        const int ocb = m * 32 + q * 8 + 4 * hi;
        ushort4 o;
        o.x = f2bf(acc[m][nn][q * 4 + 0]);
        o.y = f2bf(acc[m][nn][q * 4 + 1]);
        o.z = f2bf(acc[m][nn][q * 4 + 2]);
        o.w = f2bf(acc[m][nn][q * 4 + 3]);
        *(ushort4*)(out + obase + (size_t)px * 64 + ocb) = o;
      }
    }

  float sv[2][16], qv[2][16];
#pragma unroll
  for (int m = 0; m < 2; ++m)
#pragma unroll
    for (int r = 0; r < 16; ++r) {
      const float a0 = acc[m][0][r], a1 = acc[m][1][r];
      sv[m][r] = a0 + a1;
      qv[m][r] = a0 * a0 + a1 * a1;
    }
#pragma unroll
  for (int m = 0; m < 2; ++m)
#pragma unroll
    for (int r = 0; r < 16; ++r) {
      sv[m][r] += __shfl_xor(sv[m][r], 16);
      qv[m][r] += __shfl_xor(qv[m][r], 16);
    }
  __syncthreads();
  float* fS = (float*)a_s;            // [4][64][17]
  float* fQ = fS + 4 * 64 * 17;
  if ((lane & 31) < 16) {
    const int l16 = lane & 15;
#pragma unroll
    for (int m = 0; m < 2; ++m)
#pragma unroll
      for (int r = 0; r < 16; ++r) {
        const int oc = m * 32 + (r & 3) + 8 * (r >> 2) + 4 * hi;
        fS[(wv * 64 + oc) * 17 + l16] = sv[m][r];
        fQ[(wv * 64 + oc) * 17 + l16] = qv[m][r];
      }
  }
  __syncthreads();
  {
    const int oc = t & 63, sub = t >> 6;
    float s = 0.f, q = 0.f;
#pragma unroll
    for (int j = 0; j < 16; ++j) {
      s += fS[(sub * 64 + oc) * 17 + j];
      q += fQ[(sub * 64 + oc) * 17 + j];
    }
    s_finS[sub][oc] = s; s_finQ[sub][oc] = q;
  }
  __syncthreads();
  if (t < 64) {
    psum[(size_t)t * NPB + b] = s_finS[0][t] + s_finS[1][t] + s_finS[2][t] + s_finS[3][t];
    psq [(size_t)t * NPB + b] = s_finQ[0][t] + s_finQ[1][t] + s_finQ[2][t] + s_finQ[3][t];
  }
}

// ---- BN stats finalize: one block per channel, coalesced partial reduce
__global__ __launch_bounds__(256)
void k_bnfin(const float* __restrict__ psum, const float* __restrict__ psq,
             const float* __restrict__ g, const float* __restrict__ be,
             float* __restrict__ bnp, int nb) {
  __shared__ float s1[256], s2[256];
  const int c = blockIdx.x;
  const int t = threadIdx.x;
  float s = 0.f, q = 0.f;
  for (int j = t; j < nb; j += 256) {
    s += psum[(size_t)c * NPB + j];
    q += psq[(size_t)c * NPB + j];
  }
  s1[t] = s; s2[t] = q;
  __syncthreads();
  for (int st = 128; st > 0; st >>= 1) {
    if (t < st) { s1[t] += s1[t + st]; s2[t] += s2[t + st]; }
    __syncthreads();
  }
  if (t == 0) {
    const float m = s1[0] / PTOTF;
    const float var = s2[0] / PTOTF - m * m;
    const float sc = g[c] * rsqrtf(var + 1e-5f);
    bnp[c] = sc;
    bnp[64 + c] = be[c] - m * sc;
  }
}

// ---- elementwise: RES=0: a = celu(bn(y));  RES=1: a += celu(bn(y))
template<int RES>
__global__ __launch_bounds__(256)
void k_apply(const unsigned short* __restrict__ y, const float* __restrict__ bnp,
             unsigned short* __restrict__ a) {
  const size_t gid = (size_t)blockIdx.x * 256 + threadIdx.x;
  const int px = (int)(gid >> 3);
  const int c0 = ((int)gid & 7) * 8;
  const int n = px >> 16, hh = (px >> 8) & 255, ww = px & 255;
  const size_t i = padpx(n, hh, ww) * 64 + c0;
  float v[8];
  unpack8(*(const uint4*)(y + i), v);
  const float4 sa = *(const float4*)(bnp + c0);
  const float4 sb = *(const float4*)(bnp + c0 + 4);
  const float4 ha = *(const float4*)(bnp + 64 + c0);
  const float4 hb = *(const float4*)(bnp + 64 + c0 + 4);
  const float sc[8] = {sa.x, sa.y, sa.z, sa.w, sb.x, sb.y, sb.z, sb.w};
  const float sh[8] = {ha.x, ha.y, ha.z, ha.w, hb.x, hb.y, hb.z, hb.w};
  float r[8];
#pragma unroll
  for (int q = 0; q < 8; ++q) r[q] = celuf(v[q] * sc[q] + sh[q]);
  if (RES) {
    float av[8];
    unpack8(*(const uint4*)(a + i), av);
#pragma unroll
    for (int q = 0; q < 8; ++q) r[q] += av[q];
  }
  uint4 o;
  o.x = (unsigned)f2bf(r[0]) | ((unsigned)f2bf(r[1]) << 16);
  o.y = (unsigned)f2bf(r[2]) | ((unsigned)f2bf(r[3]) << 16);
  o.z = (unsigned)f2bf(r[4]) | ((unsigned)f2bf(r[5]) << 16);
  o.w = (unsigned)f2bf(r[6]) | ((unsigned)f2bf(r[7]) << 16);
  *(uint4*)(a + i) = o;
}

// ---- last conv 64->3 + bias + celu + x. Tile-staged, 1 thread/px, 3 oc accs.
__global__ __launch_bounds__(256, 2)
void k_last(const unsigned short* __restrict__ a, const float* __restrict__ x,
            const float* __restrict__ wl, const float* __restrict__ b2,
            float* __restrict__ outp) {
  __shared__ __align__(16) unsigned short a_s[3168 * 8];  // 50688 B
  __shared__ float wsm[3][576];                           // [oc][tap*64+ic]

  const int t = threadIdx.x;
  const int lane = t & 63, wv = t >> 6;
  int b = blockIdx.x;
  b = (b & 7) * 256 + (b >> 3);  // XCD swizzle
  const int n  = b >> 8;
  const int h0 = ((b >> 2) & 63) * 4;
  const int w0 = (b & 3) * 64;

  const size_t ibase = ((size_t)n * 258 + h0) * 258 + w0;
  for (int seg = wv; seg < 54; seg += 4) {
    const int r = seg / 9;
    const int p = seg - r * 9;
    const int c = p * 64 + lane;
    const int px = c >> 3;
    const int R = r * 66 + px;
    const int sl = (c & 7) ^ (R & 7);
    const unsigned short* gsrc = a + (ibase + (size_t)r * 258 + px) * 64 + sl * 8;
    unsigned short* ldst = a_s + (size_t)(r * 528 + p * 64) * 8;
    if (c < 528) gload16(gsrc, ldst);
  }
  for (int j = t; j < 1728; j += 256) {
    const int oc = j / 576, k = j - oc * 576;
    const int tap = k >> 6, ic = k & 63;
    wsm[oc][k] = wl[tap * 256 + ic * 4 + oc];
  }
  __syncthreads();

  const int px = lane;   // wave wv owns output row h0+wv
  float o0 = 0.f, o1 = 0.f, o2 = 0.f;
#pragma unroll 1
  for (int tap = 0; tap < 9; ++tap) {
    const int dh = tap / 3, dw = tap - dh * 3;
    const int R = (wv + dh) * 66 + px + dw;
#pragma unroll
    for (int sl = 0; sl < 8; ++sl) {
      const uint4 u = *(const uint4*)((const char*)a_s +
          (size_t)R * 128 + ((sl ^ (R & 7)) << 4));
      float v[8];
      unpack8(u, v);
      const float* wp0 = &wsm[0][tap * 64 + sl * 8];
      const float* wp1 = &wsm[1][tap * 64 + sl * 8];
      const float* wp2 = &wsm[2][tap * 64 + sl * 8];
#pragma unroll
      for (int q = 0; q < 8; ++q) {
        o0 += v[q] * wp0[q];
        o1 += v[q] * wp1[q];
        o2 += v[q] * wp2[q];
      }
    }
  }
  const int h = h0 + wv;
  const size_t ob = (size_t)n * 3 * HW + ((size_t)h << 8) + w0 + px;
  outp[ob]           = celuf(o0 + b2[0]) + x[ob];
  outp[ob + HW]      = celuf(o1 + b2[1]) + x[ob + HW];
  outp[ob + 2 * HW]  = celuf(o2 + b2[2]) + x[ob + 2 * HW];
}

extern "C" void kernel_launch(void* const* d_in, const int* in_sizes, int n_in,
                              void* d_out, int out_size, void* d_ws, size_t ws_size,
                              hipStream_t stream) {
  const float* x   = (const float*)d_in[0];
  const float* w1  = (const float*)d_in[1];
  // d_in[2] = b1 (cancels under BN)
  const float* g1  = (const float*)d_in[3];
  const float* be1 = (const float*)d_in[4];
  const float* bw  = (const float*)d_in[5];
  // d_in[6] = bb (cancels under BN)
  const float* bg  = (const float*)d_in[7];
  const float* bbe = (const float*)d_in[8];
  const float* w2  = (const float*)d_in[9];
  const float* b2  = (const float*)d_in[10];
  float* out = (float*)d_out;

  const size_t PADBUF = (size_t)8 * 258 * 258 * 64 * 2;  // bytes
  size_t off = 0;
  auto alloc = [&](size_t bytes) {
    size_t cur = off;
    off += (bytes + 255) & ~(size_t)255;
    return cur;
  };
  const size_t oA   = alloc(PADBUF);
  const size_t oB   = alloc(PADBUF);
  const size_t oC   = alloc(PADBUF);
  const size_t oW1  = alloc(4608 * 4);
  const size_t oWM  = alloc((size_t)6 * 36864 * 2);  // bf16 [cv][9][64][64]
  const size_t oWL  = alloc(2304 * 4);
  const size_t oMS  = alloc(48 * 4);
  const size_t oBNP = alloc(7 * 128 * 4);
  const size_t oPS  = alloc((size_t)64 * NPB * 4);
  const size_t oPQ  = alloc((size_t)64 * NPB * 4);
  if (off > ws_size) return;

  char* wsb = (char*)d_ws;
  unsigned short* bufA = (unsigned short*)(wsb + oA);
  unsigned short* bufB = (unsigned short*)(wsb + oB);
  unsigned short* bufC = (unsigned short*)(wsb + oC);
  float* wt1 = (float*)(wsb + oW1);
  unsigned short* wtm = (unsigned short*)(wsb + oWM);
  float* wtl = (float*)(wsb + oWL);
  float* ms  = (float*)(wsb + oMS);
  float* bnp = (float*)(wsb + oBNP);
  float* psum = (float*)(wsb + oPS);
  float* psq  = (float*)(wsb + oPQ);

  k_prep<<<988, 256, 0, stream>>>(w1, bw, w2, wt1, wtm, wtl, bufA, bufB, bufC);
  k_inorm<<<24, 256, 0, stream>>>(x, ms);

  // conv1 (6->64) -> raw bufB + fused stats; act0 -> bufA
  k_conv1<<<8192, 256, 0, stream>>>(x, ms, wt1, bufB, psum, psq);
  k_bnfin<<<64, 256, 0, stream>>>(psum, psq, g1, be1, bnp, 8192);
  k_apply<0><<<16384, 256, 0, stream>>>(bufB, bnp, bufA);

  for (int i = 0; i < 3; ++i) {
    const int s1 = 1 + 2 * i, s2 = 2 + 2 * i;
    // conv A (act) -> B raw
    k_mconv<<<2048, 256, 0, stream>>>(bufA, wtm + (size_t)(2 * i) * 36864,
                                      bufB, psum, psq);
    k_bnfin<<<64, 256, 0, stream>>>(psum, psq, bg + (size_t)(2 * i) * 64,
        bbe + (size_t)(2 * i) * 64, bnp + (size_t)s1 * 128, 2048);
    // act mid -> C
    k_apply<0><<<16384, 256, 0, stream>>>(bufB, bnp + (size_t)s1 * 128, bufC);
    // conv C (act) -> B raw
    k_mconv<<<2048, 256, 0, stream>>>(bufC, wtm + (size_t)(2 * i + 1) * 36864,
                                      bufB, psum, psq);
    k_bnfin<<<64, 256, 0, stream>>>(psum, psq, bg + (size_t)(2 * i + 1) * 64,
        bbe + (size_t)(2 * i + 1) * 64, bnp + (size_t)s2 * 128, 2048);
    // residual: A += celu(bn(B))
    k_apply<1><<<16384, 256, 0, stream>>>(bufB, bnp + (size_t)s2 * 128, bufA);
  }

  k_last<<<2048, 256, 0, stream>>>(bufA, x, wtl, b2, out);
}